// Round 8
// baseline (615.809 us; speedup 1.0000x reference)
//
#include <hip/hip_runtime.h>

#define SS 336
#define VV 8
#define DD 256
#define DKK 32
#define NTOK 5376            // B*V*S = B*S*V tokens
#define NTD (NTOK * DD)      // 1376256 elements per activation buffer
#define ATT_SCALE 0.17677669529663687f  // 1/sqrt(32)
#define LN_EPS 1e-5f

typedef _Float16 f16x8 __attribute__((ext_vector_type(8)));
typedef _Float16 f16x4v __attribute__((ext_vector_type(4)));
typedef __attribute__((ext_vector_type(4))) float f32x4;

__device__ inline _Float16 f2h(float f) { return (_Float16)f; }

// ---------------- fused init: weight prep + embed + out=bias ----------------
// blocks 0..1023: WT2 frag prep (z = bid>>8). blocks 1024..6399: embed token.
// block 0 also seeds out with the projection bias (k_proj accumulates on top).
__global__ __launch_bounds__(256) void k_init(
    const float* __restrict__ Wq, const float* __restrict__ Wk,
    const float* __restrict__ Wv, const float* __restrict__ Wo,
    const float* __restrict__ x, const float* __restrict__ ew,
    const float* __restrict__ eb, const float* __restrict__ PB,
    _Float16* __restrict__ WT2, float* __restrict__ E,
    _Float16* __restrict__ E16, float* __restrict__ out) {
  int bid = blockIdx.x;
  int tid = threadIdx.x;
  if (bid < 1024) {
    int z = bid >> 8;
    const float* W = (z == 0) ? Wq : (z == 1) ? Wk : (z == 2) ? Wv : Wo;
    int o = (bid & 255) * 256 + tid;          // 0..65535
    int blk = o >> 9;                          // ntile*8 + kb
    int idx = o & 511;
    int lane = idx >> 3, j = idx & 7;
    int nt = blk >> 3, kb = blk & 7;
    int lcol = lane & 15, quad = lane >> 4;
    int n = nt * 16 + lcol;
    int k = kb * 32 + quad * 8 + j;
    WT2[(size_t)z * 65536 + o] = f2h(W[k * 256 + n]);
    if (bid == 0) {
      for (int i = tid; i < 1536; i += 256) {
        int row = i / 96, p = i - row * 96;
        out[(row >> 3) * 768 + p * 8 + (row & 7)] = PB[p];
      }
    }
  } else {
    int token = bid - 1024;            // (b*V+v)*S + s
    int n = token / SS, s = token - n * SS;
    int b = n >> 3, v = n & 7;
    float xv = x[(b * SS + s) * VV + v];
    int d = tid;
    float val = fmaf(xv, ew[d], eb[d]);
    E[token * DD + d] = val;
    E16[token * DD + d] = f2h(val);
  }
}

// ---------------- time attention (mode0: QKV from global; mode1: in-LDS QKV)
// grid (2, 8, 16) = 256 blocks x 512 thr (8 waves).
// mode1 (it=0 only): per-head QKV mini-GEMM from Et16 (R5-verified path) --
// replaces the pre-loop k_gemm_qkv dispatch. mode0 (it>=1): R3-verified path
// reading Q16/K16/V16 produced by k_mega_var's fused nextQKV.
#define KSTR 36
#define VTSTR 344
#define PSTR 72
#define QSTR 40
__global__ __launch_bounds__(512) void k_attn_time(
    const _Float16* __restrict__ Et16, const _Float16* __restrict__ Q16,
    const _Float16* __restrict__ K16, const _Float16* __restrict__ V16,
    const _Float16* __restrict__ WT2,
    const float* __restrict__ bq, const float* __restrict__ bk,
    const float* __restrict__ bv, _Float16* __restrict__ O16, int mode) {
  int qg = blockIdx.x, h = blockIdx.y, n = blockIdx.z;
  int tid = threadIdx.x;
  int wave = tid >> 6, lane = tid & 63;
  int quad = lane >> 4, lcol = lane & 15;

  // LDS layout (bytes):
  //   [0,24192)       Ks   336 x 36 f16
  //   [24192,46240)   Vt   (32*344+16) f16
  //   mode0: Ps at 46240 (8 x 16 x 72 f16)
  //   mode1: Qs 46240 (11x16x40), Wl 60320 (6x8x512), Ach 109472 (64x264);
  //          Ps overlays Wl at 60320 after the QKV phase.
  __shared__ __align__(16) char SMRAW[143264];
  _Float16* Ks  = (_Float16*)SMRAW;
  _Float16* Vt  = (_Float16*)(SMRAW + 24192);
  _Float16* Qs  = (_Float16*)(SMRAW + 46240);
  _Float16* Wl  = (_Float16*)(SMRAW + 60320);
  _Float16* Ach = (_Float16*)(SMRAW + 109472);
  _Float16* PsB = (_Float16*)(mode ? SMRAW + 60320 : SMRAW + 46240);

  const size_t ebase = (size_t)(n * SS) * DD;
  const size_t base  = ebase + h * DKK;
  int qt0 = qg ? 11 : 0;
  int qtend = qg ? 21 : 11;

  const f32x4 z4 = {0.f, 0.f, 0.f, 0.f};

  if (mode) {
    // ---- QKV from Et16 (R5 path): W slices, then 6 m-chunks ----
    {
      int h2 = h * 2;
      for (int c = tid; c < 3072; c += 512) {
        int ot = c >> 9, rest = c & 511;
        int z = (ot < 2) ? 1 : (ot < 4) ? 2 : 0;
        int nt = h2 + (ot & 1);
        *(f16x8*)&Wl[(ot << 12) + rest * 8] =
            *(const f16x8*)&WT2[(size_t)z * 65536 + nt * 4096 + rest * 8];
      }
      for (int c = tid; c < 272; c += 512) {
        if (c < 256) {
          int d = c >> 3, col = 336 + (c & 7);
          Vt[d * VTSTR + col] = (_Float16)0.f;
        } else {
          Vt[32 * VTSTR + (c - 256)] = (_Float16)0.f;
        }
      }
    }
    for (int ck = 0; ck < 6; ++ck) {
      int m0c = ck * 64;
      int nmt = (ck < 5) ? 4 : 1;
      __syncthreads();
      for (int c = tid; c < nmt * 16 * 32; c += 512) {
        int row = c >> 5, seg = c & 31;
        *(f16x8*)&Ach[row * 264 + seg * 8] =
            *(const f16x8*)&Et16[ebase + (size_t)(m0c + row) * 256 + seg * 8];
      }
      __syncthreads();
      int nU = nmt * 6;
      for (int u = wave; u < nU; u += 8) {
        int mtl = u / 6, ot = u % 6;
        int gt = ck * 4 + mtl;
        if (ot >= 4 && (gt < qt0 || gt >= qtend)) continue;
        f32x4 acc = z4;
#pragma unroll
        for (int kb = 0; kb < 8; ++kb) {
          f16x8 af = *(const f16x8*)&Ach[(mtl * 16 + lcol) * 264 + kb * 32 + quad * 8];
          f16x8 wf = *(const f16x8*)&Wl[(ot << 12) + kb * 512 + lane * 8];
          acc = __builtin_amdgcn_mfma_f32_16x16x32_f16(af, wf, acc, 0, 0, 0);
        }
        int dlo = ((ot & 1) << 4) + lcol;
        const float* bz = (ot < 2) ? bk : (ot < 4) ? bv : bq;
        float bval = bz[h * 32 + dlo];
        if (ot < 2) {
#pragma unroll
          for (int i = 0; i < 4; ++i)
            Ks[(m0c + mtl * 16 + quad * 4 + i) * KSTR + dlo] = f2h(acc[i] + bval);
        } else if (ot < 4) {
#pragma unroll
          for (int i = 0; i < 4; ++i)
            Vt[dlo * VTSTR + (m0c + mtl * 16 + quad * 4 + i)] = f2h(acc[i] + bval);
        } else {
          int ql = gt - qt0;
#pragma unroll
          for (int i = 0; i < 4; ++i)
            Qs[(ql * 16 + quad * 4 + i) * QSTR + dlo] = f2h(acc[i] + bval);
        }
      }
    }
    __syncthreads();   // Ks/Vt/Qs ready; Wl/Ach dead -> Ps may overlay
  } else {
    // ---- stage K/V from global (R3 path) ----
    for (int c = tid; c < 1344; c += 512) {
      int row = c >> 2, part = c & 3;
      f16x8 kv = *(const f16x8*)&K16[base + (size_t)row * DD + part * 8];
      f16x4v klo = __builtin_shufflevector(kv, kv, 0, 1, 2, 3);
      f16x4v khi = __builtin_shufflevector(kv, kv, 4, 5, 6, 7);
      *(f16x4v*)&Ks[row * KSTR + part * 8] = klo;
      *(f16x4v*)&Ks[row * KSTR + part * 8 + 4] = khi;
      f16x8 vv = *(const f16x8*)&V16[base + (size_t)row * DD + part * 8];
#pragma unroll
      for (int j = 0; j < 8; ++j) Vt[(part * 8 + j) * VTSTR + row] = vv[j];
    }
    for (int c = tid; c < 272; c += 512) {
      if (c < 256) {
        int d = c >> 3, col = 336 + (c & 7);
        Vt[d * VTSTR + col] = (_Float16)0.f;
      } else {
        Vt[32 * VTSTR + (c - 256)] = (_Float16)0.f;
      }
    }
    __syncthreads();
  }

  // ---- flash attention over 336 keys (KVBLK=64, R3-verified) ----
  _Float16* P = PsB + wave * (16 * PSTR);
  const f16x8 onesv = {(_Float16)1.f, (_Float16)1.f, (_Float16)1.f, (_Float16)1.f,
                       (_Float16)1.f, (_Float16)1.f, (_Float16)1.f, (_Float16)1.f};

  for (int qtile = qt0 + wave; qtile < qtend; qtile += 8) {
    int qb = qtile * 16;
    int ql = qtile - qt0;

    f16x8 qf;
    if (mode)
      qf = *(const f16x8*)&Qs[(ql * 16 + lcol) * QSTR + quad * 8];
    else
      qf = *(const f16x8*)&Q16[base + (size_t)(qb + lcol) * DD + quad * 8];
    f32x4 accA = {0.f, 0.f, 0.f, 0.f};
    f32x4 accB = {0.f, 0.f, 0.f, 0.f};
    f32x4 lacc = {0.f, 0.f, 0.f, 0.f};
    float m_[4] = {-1e30f, -1e30f, -1e30f, -1e30f};

    // 336 = 5*64 + 16: T=0..4 full 64-key blocks, T=5 tail (16 keys)
    for (int T = 0; T < 6; ++T) {
      int k0 = T * 64;
      bool full = (T < 5);
      f32x4 s[4];
      {
        const _Float16* kp = &Ks[(k0 + lcol) * KSTR + quad * 8];
        f16x4v a0 = *(const f16x4v*)kp;
        f16x4v b0 = *(const f16x4v*)(kp + 4);
        f16x8 kf = __builtin_shufflevector(a0, b0, 0, 1, 2, 3, 4, 5, 6, 7);
        s[0] = __builtin_amdgcn_mfma_f32_16x16x32_f16(qf, kf, z4, 0, 0, 0);
      }
      if (full) {
#pragma unroll
        for (int u = 1; u < 4; ++u) {
          const _Float16* kp = &Ks[(k0 + u * 16 + lcol) * KSTR + quad * 8];
          f16x4v a0 = *(const f16x4v*)kp;
          f16x4v b0 = *(const f16x4v*)(kp + 4);
          f16x8 kf = __builtin_shufflevector(a0, b0, 0, 1, 2, 3, 4, 5, 6, 7);
          s[u] = __builtin_amdgcn_mfma_f32_16x16x32_f16(qf, kf, z4, 0, 0, 0);
        }
      } else {
        s[1] = z4; s[2] = z4; s[3] = z4;
      }
      float sc[4][4], p[4][4], corr[4];
#pragma unroll
      for (int u = 0; u < 4; ++u)
#pragma unroll
        for (int i = 0; i < 4; ++i)
          sc[u][i] = (u == 0 || full) ? s[u][i] * ATT_SCALE : -1e30f;
#pragma unroll
      for (int i = 0; i < 4; ++i) {
        float t2 = fmaxf(fmaxf(sc[0][i], sc[1][i]), fmaxf(sc[2][i], sc[3][i]));
        t2 = fmaxf(t2, __shfl_xor(t2, 1));
        t2 = fmaxf(t2, __shfl_xor(t2, 2));
        t2 = fmaxf(t2, __shfl_xor(t2, 4));
        t2 = fmaxf(t2, __shfl_xor(t2, 8));
        float nm = fmaxf(m_[i], t2);
        corr[i] = __expf(m_[i] - nm);
        m_[i] = nm;
#pragma unroll
        for (int u = 0; u < 4; ++u) p[u][i] = __expf(sc[u][i] - nm);
        accA[i] *= corr[i];
        accB[i] *= corr[i];
        lacc[i] *= corr[i];
      }
#pragma unroll
      for (int i = 0; i < 4; ++i)
#pragma unroll
        for (int u = 0; u < 4; ++u)
          P[(quad * 4 + i) * PSTR + u * 16 + lcol] = f2h(p[u][i]);
      f16x8 pf0 = *(const f16x8*)&P[lcol * PSTR + quad * 8];
      lacc = __builtin_amdgcn_mfma_f32_16x16x32_f16(pf0, onesv, lacc, 0, 0, 0);
      f16x8 va0 = *(const f16x8*)&Vt[lcol * VTSTR + k0 + quad * 8];
      f16x8 vb0 = *(const f16x8*)&Vt[(16 + lcol) * VTSTR + k0 + quad * 8];
      accA = __builtin_amdgcn_mfma_f32_16x16x32_f16(pf0, va0, accA, 0, 0, 0);
      accB = __builtin_amdgcn_mfma_f32_16x16x32_f16(pf0, vb0, accB, 0, 0, 0);
      if (full) {
        f16x8 pf1 = *(const f16x8*)&P[lcol * PSTR + 32 + quad * 8];
        lacc = __builtin_amdgcn_mfma_f32_16x16x32_f16(pf1, onesv, lacc, 0, 0, 0);
        f16x8 va1 = *(const f16x8*)&Vt[lcol * VTSTR + k0 + 32 + quad * 8];
        f16x8 vb1 = *(const f16x8*)&Vt[(16 + lcol) * VTSTR + k0 + 32 + quad * 8];
        accA = __builtin_amdgcn_mfma_f32_16x16x32_f16(pf1, va1, accA, 0, 0, 0);
        accB = __builtin_amdgcn_mfma_f32_16x16x32_f16(pf1, vb1, accB, 0, 0, 0);
      }
    }

#pragma unroll
    for (int i = 0; i < 4; ++i) {
      float inv = 1.f / lacc[i];
      P[(quad * 4 + i) * PSTR + lcol] = f2h(accA[i] * inv);
      P[(quad * 4 + i) * PSTR + 16 + lcol] = f2h(accB[i] * inv);
    }
    int row = lane >> 2, seg = lane & 3;
    f16x8 ov = *(const f16x8*)&P[row * PSTR + seg * 8];
    *(f16x8*)&O16[base + (size_t)(qb + row) * DD + seg * 8] = ov;
  }
}

// ---------------- MEGA var stage (32 rows/block, 8 waves) + fused next-QKV -
// grid 168 x 512thr; R3-verified version (571.8us loop).
__global__ __launch_bounds__(512) void k_mega_var(
    const _Float16* __restrict__ AO16, const _Float16* __restrict__ WT2,
    const float* __restrict__ bq, const float* __restrict__ bk,
    const float* __restrict__ bv, const float* __restrict__ bo,
    const float* __restrict__ g1, const float* __restrict__ c1,
    const float* __restrict__ gn, const float* __restrict__ bn,
    float* __restrict__ Etime, _Float16* __restrict__ Q16,
    _Float16* __restrict__ K16, _Float16* __restrict__ V16, int doqkv) {
  int tid = threadIdx.x;
  int wave = tid >> 6, lane = tid & 63;
  int quad = lane >> 4, lcol = lane & 15;

  __shared__ int rmapS[32];
  __shared__ _Float16 Af[32 * 264];    // 16.5 KB
  __shared__ float Cf[32 * 260];       // 33.3 KB
  __shared__ _Float16 QKVs[32 * 776];  // 48.5 KB

  if (tid < 32) {
    int r2 = blockIdx.x * 32 + tid;
    int n_idx = r2 >> 3, v = r2 & 7;
    int b = n_idx / SS, s = n_idx - b * SS;
    rmapS[tid] = (b * VV + v) * SS + s;
  }
  __syncthreads();

  // stage AO rows (time layout, gathered) into Af
  {
    int row = tid >> 4, seg = tid & 15;
    const _Float16* src = AO16 + (size_t)rmapS[row] * DD + seg * 16;
    _Float16* dst = Af + row * 264 + seg * 16;
    *(f16x8*)(dst) = *(const f16x8*)(src);
    *(f16x8*)(dst + 8) = *(const f16x8*)(src + 8);
  }
  __syncthreads();

  const _Float16* WoF = WT2 + (size_t)3 * 65536;   // Wo frag block

  // ---- time O-proj: Cf = Af @ Wo + bo + Etime(res) ----
  {
    f32x4 acc[2][2] = {};
    for (int kb = 0; kb < 8; ++kb) {
      int k0 = kb * 32;
      f16x8 af0 = *(const f16x8*)&Af[lcol * 264 + k0 + quad * 8];
      f16x8 af1 = *(const f16x8*)&Af[(16 + lcol) * 264 + k0 + quad * 8];
#pragma unroll
      for (int nt = 0; nt < 2; ++nt) {
        f16x8 bfr = *(const f16x8*)&WoF[((wave * 2 + nt) * 8 + kb) * 512 + lane * 8];
        acc[0][nt] = __builtin_amdgcn_mfma_f32_16x16x32_f16(af0, bfr, acc[0][nt], 0, 0, 0);
        acc[1][nt] = __builtin_amdgcn_mfma_f32_16x16x32_f16(af1, bfr, acc[1][nt], 0, 0, 0);
      }
    }
#pragma unroll
    for (int mt = 0; mt < 2; ++mt) {
#pragma unroll
      for (int i = 0; i < 4; ++i) {
        int row = mt * 16 + quad * 4 + i;
        size_t rb = (size_t)rmapS[row] * 256;
#pragma unroll
        for (int nt = 0; nt < 2; ++nt) {
          int col = (wave * 2 + nt) * 16 + lcol;
          Cf[row * 260 + col] = acc[mt][nt][i] + bo[col] + Etime[rb + col];
        }
      }
    }
  }
  __syncthreads();

  // ---- double LN (ln1 then norm); write Cf fp32 + Af f16 ----
  {
    int row = tid >> 4, c0 = (tid & 15) * 16;
    float v[16];
#pragma unroll
    for (int j = 0; j < 16; ++j) v[j] = Cf[row * 260 + c0 + j];
#pragma unroll
    for (int pass = 0; pass < 2; ++pass) {
      const float* gg = pass ? gn : g1;
      const float* bb = pass ? bn : c1;
      float s = 0.f, q = 0.f;
#pragma unroll
      for (int j = 0; j < 16; ++j) { s += v[j]; q = fmaf(v[j], v[j], q); }
      s += __shfl_xor(s, 1); q += __shfl_xor(q, 1);
      s += __shfl_xor(s, 2); q += __shfl_xor(q, 2);
      s += __shfl_xor(s, 4); q += __shfl_xor(q, 4);
      s += __shfl_xor(s, 8); q += __shfl_xor(q, 8);
      float mu = s * (1.0f / 256.0f);
      float rs = rsqrtf(q * (1.0f / 256.0f) - mu * mu + LN_EPS);
#pragma unroll
      for (int j = 0; j < 16; ++j)
        v[j] = fmaf((v[j] - mu) * rs, gg[c0 + j], bb[c0 + j]);
    }
#pragma unroll
    for (int j = 0; j < 16; ++j) Cf[row * 260 + c0 + j] = v[j];
#pragma unroll
    for (int j8 = 0; j8 < 2; ++j8) {
      f16x8 h;
#pragma unroll
      for (int jj = 0; jj < 8; ++jj) h[jj] = f2h(v[j8 * 8 + jj]);
      *(f16x8*)&Af[row * 264 + c0 + j8 * 8] = h;
    }
  }
  __syncthreads();

  // ---- var QKV: QKVs[32][768] = Af @ {Wq|Wk|Wv} + bias ----
  {
    f32x4 acc[2][6] = {};
    for (int kb = 0; kb < 8; ++kb) {
      int k0 = kb * 32;
      f16x8 af0 = *(const f16x8*)&Af[lcol * 264 + k0 + quad * 8];
      f16x8 af1 = *(const f16x8*)&Af[(16 + lcol) * 264 + k0 + quad * 8];
#pragma unroll
      for (int j = 0; j < 6; ++j) {
        int ntg = wave * 6 + j;                   // 0..47 == z*16 + ntile
        f16x8 bfr = *(const f16x8*)&WT2[(size_t)(ntg * 8 + kb) * 512 + lane * 8];
        acc[0][j] = __builtin_amdgcn_mfma_f32_16x16x32_f16(af0, bfr, acc[0][j], 0, 0, 0);
        acc[1][j] = __builtin_amdgcn_mfma_f32_16x16x32_f16(af1, bfr, acc[1][j], 0, 0, 0);
      }
    }
#pragma unroll
    for (int j = 0; j < 6; ++j) {
      int ntg = wave * 6 + j;
      int colb = ntg * 16;
      int z = colb >> 8, coln = (colb & 255) + lcol;
      const float* bz = (z == 0) ? bq : (z == 1) ? bk : bv;
      float bval = bz[coln];
#pragma unroll
      for (int mt = 0; mt < 2; ++mt) {
#pragma unroll
        for (int i = 0; i < 4; ++i)
          QKVs[(mt * 16 + quad * 4 + i) * 776 + colb + lcol] = f2h(acc[mt][j][i] + bval);
      }
    }
  }
  __syncthreads();

  // ---- var attention: all 512 thr; thread pairs split the 32 dims ----
  {
    int half = tid & 1, qi = (tid >> 1) & 7, h = (tid >> 4) & 7, ng = tid >> 7;
    int d0 = h * 32 + half * 16;
    const _Float16* Qp = &QKVs[(ng * 8 + qi) * 776 + d0];
    float qv[16];
#pragma unroll
    for (int j8 = 0; j8 < 2; ++j8) {
      f16x8 t = *(const f16x8*)(Qp + j8 * 8);
#pragma unroll
      for (int jj = 0; jj < 8; ++jj) qv[j8 * 8 + jj] = (float)t[jj];
    }
    float sc[8];
#pragma unroll
    for (int k = 0; k < 8; ++k) {
      const _Float16* Kp = &QKVs[(ng * 8 + k) * 776 + 256 + d0];
      float s = 0.f;
#pragma unroll
      for (int j8 = 0; j8 < 2; ++j8) {
        f16x8 t = *(const f16x8*)(Kp + j8 * 8);
#pragma unroll
        for (int jj = 0; jj < 8; ++jj) s = fmaf(qv[j8 * 8 + jj], (float)t[jj], s);
      }
      sc[k] = s;
    }
#pragma unroll
    for (int k = 0; k < 8; ++k)
      sc[k] = (sc[k] + __shfl_xor(sc[k], 1)) * ATT_SCALE;
    float mx = sc[0];
#pragma unroll
    for (int k = 1; k < 8; ++k) mx = fmaxf(mx, sc[k]);
    float ps = 0.f;
#pragma unroll
    for (int k = 0; k < 8; ++k) { sc[k] = __expf(sc[k] - mx); ps += sc[k]; }
    float inv = 1.f / ps;
    float ov[16];
#pragma unroll
    for (int j = 0; j < 16; ++j) ov[j] = 0.f;
#pragma unroll
    for (int k = 0; k < 8; ++k) {
      const _Float16* Vp = &QKVs[(ng * 8 + k) * 776 + 512 + d0];
      float p = sc[k];
#pragma unroll
      for (int j8 = 0; j8 < 2; ++j8) {
        f16x8 t = *(const f16x8*)(Vp + j8 * 8);
#pragma unroll
        for (int jj = 0; jj < 8; ++jj)
          ov[j8 * 8 + jj] = fmaf(p, (float)t[jj], ov[j8 * 8 + jj]);
      }
    }
    _Float16* Op = &Af[(ng * 8 + qi) * 264 + d0];
#pragma unroll
    for (int j8 = 0; j8 < 2; ++j8) {
      f16x8 hh;
#pragma unroll
      for (int jj = 0; jj < 8; ++jj) hh[jj] = f2h(ov[j8 * 8 + jj] * inv);
      *(f16x8*)(Op + j8 * 8) = hh;
    }
  }
  __syncthreads();

  // ---- var O-proj: Cf = Af @ Wo + bo + Cf(res x_var) ----
  {
    f32x4 acc[2][2] = {};
    for (int kb = 0; kb < 8; ++kb) {
      int k0 = kb * 32;
      f16x8 af0 = *(const f16x8*)&Af[lcol * 264 + k0 + quad * 8];
      f16x8 af1 = *(const f16x8*)&Af[(16 + lcol) * 264 + k0 + quad * 8];
#pragma unroll
      for (int nt = 0; nt < 2; ++nt) {
        f16x8 bfr = *(const f16x8*)&WoF[((wave * 2 + nt) * 8 + kb) * 512 + lane * 8];
        acc[0][nt] = __builtin_amdgcn_mfma_f32_16x16x32_f16(af0, bfr, acc[0][nt], 0, 0, 0);
        acc[1][nt] = __builtin_amdgcn_mfma_f32_16x16x32_f16(af1, bfr, acc[1][nt], 0, 0, 0);
      }
    }
#pragma unroll
    for (int mt = 0; mt < 2; ++mt) {
#pragma unroll
      for (int i = 0; i < 4; ++i) {
        int row = mt * 16 + quad * 4 + i;
#pragma unroll
        for (int nt = 0; nt < 2; ++nt) {
          int col = (wave * 2 + nt) * 16 + lcol;
          Cf[row * 260 + col] = acc[mt][nt][i] + bo[col] + Cf[row * 260 + col];
        }
      }
    }
  }
  __syncthreads();

  // ---- final LN1 + store Etime (f32) + Af (f16, feeds fused QKV) ----
  {
    int row = tid >> 4, c0 = (tid & 15) * 16;
    float v[16];
#pragma unroll
    for (int j = 0; j < 16; ++j) v[j] = Cf[row * 260 + c0 + j];
    float s = 0.f, q = 0.f;
#pragma unroll
    for (int j = 0; j < 16; ++j) { s += v[j]; q = fmaf(v[j], v[j], q); }
    s += __shfl_xor(s, 1); q += __shfl_xor(q, 1);
    s += __shfl_xor(s, 2); q += __shfl_xor(q, 2);
    s += __shfl_xor(s, 4); q += __shfl_xor(q, 4);
    s += __shfl_xor(s, 8); q += __shfl_xor(q, 8);
    float mu = s * (1.0f / 256.0f);
    float rs = rsqrtf(q * (1.0f / 256.0f) - mu * mu + LN_EPS);
#pragma unroll
    for (int j = 0; j < 16; ++j)
      v[j] = fmaf((v[j] - mu) * rs, g1[c0 + j], c1[c0 + j]);
    size_t rb = (size_t)rmapS[row] * 256 + c0;
#pragma unroll
    for (int j4 = 0; j4 < 4; ++j4) {
      float4 f4 = make_float4(v[j4 * 4], v[j4 * 4 + 1], v[j4 * 4 + 2], v[j4 * 4 + 3]);
      *(float4*)&Etime[rb + j4 * 4] = f4;
    }
#pragma unroll
    for (int j8 = 0; j8 < 2; ++j8) {
      f16x8 hh;
#pragma unroll
      for (int jj = 0; jj < 8; ++jj) hh[jj] = f2h(v[j8 * 8 + jj]);
      *(f16x8*)&Af[row * 264 + c0 + j8 * 8] = hh;
    }
  }
  __syncthreads();

  // ---- fused next-iteration time-stage QKV (skipped on last iter) ----
  if (doqkv) {
    f32x4 acc[2][6] = {};
    for (int kb = 0; kb < 8; ++kb) {
      int k0 = kb * 32;
      f16x8 af0 = *(const f16x8*)&Af[lcol * 264 + k0 + quad * 8];
      f16x8 af1 = *(const f16x8*)&Af[(16 + lcol) * 264 + k0 + quad * 8];
#pragma unroll
      for (int j = 0; j < 6; ++j) {
        int ntg = wave * 6 + j;                   // 0..47 == z*16 + ntile
        f16x8 bfr = *(const f16x8*)&WT2[(size_t)(ntg * 8 + kb) * 512 + lane * 8];
        acc[0][j] = __builtin_amdgcn_mfma_f32_16x16x32_f16(af0, bfr, acc[0][j], 0, 0, 0);
        acc[1][j] = __builtin_amdgcn_mfma_f32_16x16x32_f16(af1, bfr, acc[1][j], 0, 0, 0);
      }
    }
#pragma unroll
    for (int j = 0; j < 6; ++j) {
      int ntg = wave * 6 + j;
      int colb = ntg * 16;
      int z = colb >> 8, coln = (colb & 255) + lcol;
      const float* bz = (z == 0) ? bq : (z == 1) ? bk : bv;
      _Float16* Hd = (z == 0) ? Q16 : (z == 1) ? K16 : V16;
      float bval = bz[coln];
#pragma unroll
      for (int mt = 0; mt < 2; ++mt) {
#pragma unroll
        for (int i = 0; i < 4; ++i) {
          int row = mt * 16 + quad * 4 + i;
          Hd[(size_t)rmapS[row] * 256 + coln] = f2h(acc[mt][j][i] + bval);
        }
      }
    }
  }
}

// ---------------- final projection: single node, g-split + f32 atomics -----
// 256 blocks x 384 thr; block owns a 336-wide k-chunk. Threads = (g 0..15,
// p4 0..23): each thread covers 21 k-values x ALL 16 rows in registers
// (acc[16] float4, static idx), giving 16x the memory-level parallelism of
// the per-row layout (R7's 336-serial-load chain was the 75us bug). Then
// 16-way LDS reduce (sm 96KB) + 98K f32 atomicAdds (known-cheap from R7).
// out pre-seeded with bias by k_init.
__global__ __launch_bounds__(384) void k_proj(
    const float* __restrict__ E, const float* __restrict__ PW,
    float* __restrict__ out) {
  __shared__ float Es[16][336];      // 21.5 KB
  __shared__ float sm[16][1536];     // 96 KB
  int tid = threadIdx.x;
  int kc0 = blockIdx.x * 336;
  for (int idx = tid; idx < 1344; idx += 384) {
    int row = idx / 84, kk4 = idx % 84;
    *(float4*)&Es[row][kk4 * 4] =
        *(const float4*)&E[(size_t)row * 86016 + kc0 + kk4 * 4];
  }
  __syncthreads();
  int g = tid / 24, p4 = tid % 24;   // g: k-split 0..15, p4: out col quad
  float4 acc[16];
#pragma unroll
  for (int r = 0; r < 16; ++r) acc[r] = make_float4(0.f, 0.f, 0.f, 0.f);
  int kbase = kc0 + g * 21;
#pragma unroll 7
  for (int j = 0; j < 21; ++j) {
    float4 w = *(const float4*)&PW[(size_t)(kbase + j) * 96 + p4 * 4];
#pragma unroll
    for (int r = 0; r < 16; ++r) {
      float e = Es[r][g * 21 + j];
      acc[r].x = fmaf(e, w.x, acc[r].x);
      acc[r].y = fmaf(e, w.y, acc[r].y);
      acc[r].z = fmaf(e, w.z, acc[r].z);
      acc[r].w = fmaf(e, w.w, acc[r].w);
    }
  }
#pragma unroll
  for (int r = 0; r < 16; ++r)
    *(float4*)&sm[g][r * 96 + p4 * 4] = acc[r];
  __syncthreads();
  for (int o = tid; o < 1536; o += 384) {
    float s = 0.f;
#pragma unroll
    for (int g2 = 0; g2 < 16; ++g2) s += sm[g2][o];
    int row = o / 96, p = o - row * 96;
    atomicAdd(&out[(row >> 3) * 768 + p * 8 + (row & 7)], s);
  }
}

// ---------------- launch ---------------------------------------------------
extern "C" void kernel_launch(void* const* d_in, const int* in_sizes, int n_in,
                              void* d_out, int out_size, void* d_ws,
                              size_t ws_size, hipStream_t stream) {
  const float* x     = (const float*)d_in[0];
  const float* emb_w = (const float*)d_in[1];
  const float* emb_b = (const float*)d_in[2];
  const float* Wq = (const float*)d_in[3];
  const float* bq = (const float*)d_in[4];
  const float* Wk = (const float*)d_in[5];
  const float* bk = (const float*)d_in[6];
  const float* Wv = (const float*)d_in[7];
  const float* bv = (const float*)d_in[8];
  const float* Wo = (const float*)d_in[9];
  const float* bo = (const float*)d_in[10];
  const float* g1 = (const float*)d_in[11];
  const float* b1 = (const float*)d_in[12];
  const float* gn = (const float*)d_in[13];
  const float* bn = (const float*)d_in[14];
  const float* PW = (const float*)d_in[15];
  const float* PB = (const float*)d_in[16];
  float* out = (float*)d_out;

  float* ws = (float*)d_ws;
  float* Etime   = ws;                              // NTD f32
  _Float16* Et16 = (_Float16*)(ws + (size_t)NTD);   // NTD f16
  _Float16* Q16  = (_Float16*)(ws + (size_t)NTD + NTD / 2);
  _Float16* K16  = Q16 + (size_t)NTD;
  _Float16* V16  = K16 + (size_t)NTD;
  _Float16* AO16 = V16 + (size_t)NTD;
  _Float16* WT2  = AO16 + (size_t)NTD;              // 4*65536 f16 (frag order)

  k_init<<<6400, 256, 0, stream>>>(Wq, Wk, Wv, Wo, x, emb_w, emb_b, PB,
                                   WT2, Etime, Et16, out);
  for (int it = 0; it < 10; ++it) {
    k_attn_time<<<dim3(2, 8, 16), 512, 0, stream>>>(
        Et16, Q16, K16, V16, WT2, bq, bk, bv, AO16, (it == 0) ? 1 : 0);
    k_mega_var<<<168, 512, 0, stream>>>(
        AO16, WT2, bq, bk, bv, bo, g1, b1, gn, bn, Etime,
        Q16, K16, V16, (it < 9) ? 1 : 0);
  }
  k_proj<<<256, 384, 0, stream>>>(Etime, PW, out);
}

// Round 9
// 578.583 us; speedup vs baseline: 1.0643x; 1.0643x over previous
//
#include <hip/hip_runtime.h>

#define SS 336
#define VV 8
#define DD 256
#define DKK 32
#define NTOK 5376            // B*V*S = B*S*V tokens
#define NTD (NTOK * DD)      // 1376256 elements per activation buffer
#define ATT_SCALE 0.17677669529663687f  // 1/sqrt(32)
#define LN_EPS 1e-5f

typedef _Float16 f16x8 __attribute__((ext_vector_type(8)));
typedef _Float16 f16x4v __attribute__((ext_vector_type(4)));
typedef __attribute__((ext_vector_type(4))) float f32x4;

__device__ inline _Float16 f2h(float f) { return (_Float16)f; }

// ---------------- fused init: W prep + embed + out=bias + PWF16 prep --------
// blocks 0..1023: WT2 frag prep. 1024..6399: embed. 6400..10431: PWF16 prep
// (proj weight in MFMA B-frag order, f16 -> halves the k_proj stream).
// PWF offset(ktile,nt,lane,j) = ((ktile*6+nt)*64+lane)*8+j holds
// PW[k][n] with k = ktile*32 + (lane>>4)*8 + j, n = nt*16 + (lane&15).
__global__ __launch_bounds__(256) void k_init(
    const float* __restrict__ Wq, const float* __restrict__ Wk,
    const float* __restrict__ Wv, const float* __restrict__ Wo,
    const float* __restrict__ x, const float* __restrict__ ew,
    const float* __restrict__ eb, const float* __restrict__ PB,
    const float* __restrict__ PW,
    _Float16* __restrict__ WT2, float* __restrict__ E,
    _Float16* __restrict__ E16, _Float16* __restrict__ PWF,
    float* __restrict__ out) {
  int bid = blockIdx.x;
  int tid = threadIdx.x;
  if (bid < 1024) {
    int z = bid >> 8;
    const float* W = (z == 0) ? Wq : (z == 1) ? Wk : (z == 2) ? Wv : Wo;
    int o = (bid & 255) * 256 + tid;          // 0..65535
    int blk = o >> 9;                          // ntile*8 + kb
    int idx = o & 511;
    int lane = idx >> 3, j = idx & 7;
    int nt = blk >> 3, kb = blk & 7;
    int lcol = lane & 15, quad = lane >> 4;
    int n = nt * 16 + lcol;
    int k = kb * 32 + quad * 8 + j;
    WT2[(size_t)z * 65536 + o] = f2h(W[k * 256 + n]);
    if (bid == 0) {
      for (int i = tid; i < 1536; i += 256) {
        int row = i / 96, p = i - row * 96;
        out[(row >> 3) * 768 + p * 8 + (row & 7)] = PB[p];
      }
    }
  } else if (bid < 6400) {
    int token = bid - 1024;            // (b*V+v)*S + s
    int n = token / SS, s = token - n * SS;
    int b = n >> 3, v = n & 7;
    float xv = x[(b * SS + s) * VV + v];
    int d = tid;
    float val = fmaf(xv, ew[d], eb[d]);
    E[token * DD + d] = val;
    E16[token * DD + d] = f2h(val);
  } else {
    int idx = (bid - 6400) * 256 + tid;  // 0..1032191 = 2688 ktiles * 6 nt * 64
    int ktile = idx / 384;
    int rem = idx - ktile * 384;
    int nt = rem >> 6, lane = rem & 63;
    int quad = lane >> 4, lcol = lane & 15;
    int k0 = ktile * 32 + quad * 8;
    int n = nt * 16 + lcol;
    f16x8 w;
#pragma unroll
    for (int j = 0; j < 8; ++j) w[j] = f2h(PW[(size_t)(k0 + j) * 96 + n]);
    *(f16x8*)&PWF[(size_t)idx * 8] = w;
  }
}

// ---------------- time attention (mode0: QKV from global; mode1: in-LDS QKV)
// grid (2, 8, 16) = 256 blocks x 512 thr (8 waves).
#define KSTR 36
#define VTSTR 344
#define PSTR 72
#define QSTR 40
__global__ __launch_bounds__(512) void k_attn_time(
    const _Float16* __restrict__ Et16, const _Float16* __restrict__ Q16,
    const _Float16* __restrict__ K16, const _Float16* __restrict__ V16,
    const _Float16* __restrict__ WT2,
    const float* __restrict__ bq, const float* __restrict__ bk,
    const float* __restrict__ bv, _Float16* __restrict__ O16, int mode) {
  int qg = blockIdx.x, h = blockIdx.y, n = blockIdx.z;
  int tid = threadIdx.x;
  int wave = tid >> 6, lane = tid & 63;
  int quad = lane >> 4, lcol = lane & 15;

  __shared__ __align__(16) char SMRAW[143264];
  _Float16* Ks  = (_Float16*)SMRAW;
  _Float16* Vt  = (_Float16*)(SMRAW + 24192);
  _Float16* Qs  = (_Float16*)(SMRAW + 46240);
  _Float16* Wl  = (_Float16*)(SMRAW + 60320);
  _Float16* Ach = (_Float16*)(SMRAW + 109472);
  _Float16* PsB = (_Float16*)(mode ? SMRAW + 60320 : SMRAW + 46240);

  const size_t ebase = (size_t)(n * SS) * DD;
  const size_t base  = ebase + h * DKK;
  int qt0 = qg ? 11 : 0;
  int qtend = qg ? 21 : 11;

  const f32x4 z4 = {0.f, 0.f, 0.f, 0.f};

  if (mode) {
    // ---- QKV from Et16 (R5 path): W slices, then 6 m-chunks ----
    {
      int h2 = h * 2;
      for (int c = tid; c < 3072; c += 512) {
        int ot = c >> 9, rest = c & 511;
        int z = (ot < 2) ? 1 : (ot < 4) ? 2 : 0;
        int nt = h2 + (ot & 1);
        *(f16x8*)&Wl[(ot << 12) + rest * 8] =
            *(const f16x8*)&WT2[(size_t)z * 65536 + nt * 4096 + rest * 8];
      }
      for (int c = tid; c < 272; c += 512) {
        if (c < 256) {
          int d = c >> 3, col = 336 + (c & 7);
          Vt[d * VTSTR + col] = (_Float16)0.f;
        } else {
          Vt[32 * VTSTR + (c - 256)] = (_Float16)0.f;
        }
      }
    }
    for (int ck = 0; ck < 6; ++ck) {
      int m0c = ck * 64;
      int nmt = (ck < 5) ? 4 : 1;
      __syncthreads();
      for (int c = tid; c < nmt * 16 * 32; c += 512) {
        int row = c >> 5, seg = c & 31;
        *(f16x8*)&Ach[row * 264 + seg * 8] =
            *(const f16x8*)&Et16[ebase + (size_t)(m0c + row) * 256 + seg * 8];
      }
      __syncthreads();
      int nU = nmt * 6;
      for (int u = wave; u < nU; u += 8) {
        int mtl = u / 6, ot = u % 6;
        int gt = ck * 4 + mtl;
        if (ot >= 4 && (gt < qt0 || gt >= qtend)) continue;
        f32x4 acc = z4;
#pragma unroll
        for (int kb = 0; kb < 8; ++kb) {
          f16x8 af = *(const f16x8*)&Ach[(mtl * 16 + lcol) * 264 + kb * 32 + quad * 8];
          f16x8 wf = *(const f16x8*)&Wl[(ot << 12) + kb * 512 + lane * 8];
          acc = __builtin_amdgcn_mfma_f32_16x16x32_f16(af, wf, acc, 0, 0, 0);
        }
        int dlo = ((ot & 1) << 4) + lcol;
        const float* bz = (ot < 2) ? bk : (ot < 4) ? bv : bq;
        float bval = bz[h * 32 + dlo];
        if (ot < 2) {
#pragma unroll
          for (int i = 0; i < 4; ++i)
            Ks[(m0c + mtl * 16 + quad * 4 + i) * KSTR + dlo] = f2h(acc[i] + bval);
        } else if (ot < 4) {
#pragma unroll
          for (int i = 0; i < 4; ++i)
            Vt[dlo * VTSTR + (m0c + mtl * 16 + quad * 4 + i)] = f2h(acc[i] + bval);
        } else {
          int ql = gt - qt0;
#pragma unroll
          for (int i = 0; i < 4; ++i)
            Qs[(ql * 16 + quad * 4 + i) * QSTR + dlo] = f2h(acc[i] + bval);
        }
      }
    }
    __syncthreads();   // Ks/Vt/Qs ready; Wl/Ach dead -> Ps may overlay
  } else {
    // ---- stage K/V from global (R3 path) ----
    for (int c = tid; c < 1344; c += 512) {
      int row = c >> 2, part = c & 3;
      f16x8 kv = *(const f16x8*)&K16[base + (size_t)row * DD + part * 8];
      f16x4v klo = __builtin_shufflevector(kv, kv, 0, 1, 2, 3);
      f16x4v khi = __builtin_shufflevector(kv, kv, 4, 5, 6, 7);
      *(f16x4v*)&Ks[row * KSTR + part * 8] = klo;
      *(f16x4v*)&Ks[row * KSTR + part * 8 + 4] = khi;
      f16x8 vv = *(const f16x8*)&V16[base + (size_t)row * DD + part * 8];
#pragma unroll
      for (int j = 0; j < 8; ++j) Vt[(part * 8 + j) * VTSTR + row] = vv[j];
    }
    for (int c = tid; c < 272; c += 512) {
      if (c < 256) {
        int d = c >> 3, col = 336 + (c & 7);
        Vt[d * VTSTR + col] = (_Float16)0.f;
      } else {
        Vt[32 * VTSTR + (c - 256)] = (_Float16)0.f;
      }
    }
    __syncthreads();
  }

  // ---- flash attention over 336 keys (KVBLK=64, R3-verified) ----
  _Float16* P = PsB + wave * (16 * PSTR);
  const f16x8 onesv = {(_Float16)1.f, (_Float16)1.f, (_Float16)1.f, (_Float16)1.f,
                       (_Float16)1.f, (_Float16)1.f, (_Float16)1.f, (_Float16)1.f};

  for (int qtile = qt0 + wave; qtile < qtend; qtile += 8) {
    int qb = qtile * 16;
    int ql = qtile - qt0;

    f16x8 qf;
    if (mode)
      qf = *(const f16x8*)&Qs[(ql * 16 + lcol) * QSTR + quad * 8];
    else
      qf = *(const f16x8*)&Q16[base + (size_t)(qb + lcol) * DD + quad * 8];
    f32x4 accA = {0.f, 0.f, 0.f, 0.f};
    f32x4 accB = {0.f, 0.f, 0.f, 0.f};
    f32x4 lacc = {0.f, 0.f, 0.f, 0.f};
    float m_[4] = {-1e30f, -1e30f, -1e30f, -1e30f};

    // 336 = 5*64 + 16: T=0..4 full 64-key blocks, T=5 tail (16 keys)
    for (int T = 0; T < 6; ++T) {
      int k0 = T * 64;
      bool full = (T < 5);
      f32x4 s[4];
      {
        const _Float16* kp = &Ks[(k0 + lcol) * KSTR + quad * 8];
        f16x4v a0 = *(const f16x4v*)kp;
        f16x4v b0 = *(const f16x4v*)(kp + 4);
        f16x8 kf = __builtin_shufflevector(a0, b0, 0, 1, 2, 3, 4, 5, 6, 7);
        s[0] = __builtin_amdgcn_mfma_f32_16x16x32_f16(qf, kf, z4, 0, 0, 0);
      }
      if (full) {
#pragma unroll
        for (int u = 1; u < 4; ++u) {
          const _Float16* kp = &Ks[(k0 + u * 16 + lcol) * KSTR + quad * 8];
          f16x4v a0 = *(const f16x4v*)kp;
          f16x4v b0 = *(const f16x4v*)(kp + 4);
          f16x8 kf = __builtin_shufflevector(a0, b0, 0, 1, 2, 3, 4, 5, 6, 7);
          s[u] = __builtin_amdgcn_mfma_f32_16x16x32_f16(qf, kf, z4, 0, 0, 0);
        }
      } else {
        s[1] = z4; s[2] = z4; s[3] = z4;
      }
      float sc[4][4], p[4][4], corr[4];
#pragma unroll
      for (int u = 0; u < 4; ++u)
#pragma unroll
        for (int i = 0; i < 4; ++i)
          sc[u][i] = (u == 0 || full) ? s[u][i] * ATT_SCALE : -1e30f;
#pragma unroll
      for (int i = 0; i < 4; ++i) {
        float t2 = fmaxf(fmaxf(sc[0][i], sc[1][i]), fmaxf(sc[2][i], sc[3][i]));
        t2 = fmaxf(t2, __shfl_xor(t2, 1));
        t2 = fmaxf(t2, __shfl_xor(t2, 2));
        t2 = fmaxf(t2, __shfl_xor(t2, 4));
        t2 = fmaxf(t2, __shfl_xor(t2, 8));
        float nm = fmaxf(m_[i], t2);
        corr[i] = __expf(m_[i] - nm);
        m_[i] = nm;
#pragma unroll
        for (int u = 0; u < 4; ++u) p[u][i] = __expf(sc[u][i] - nm);
        accA[i] *= corr[i];
        accB[i] *= corr[i];
        lacc[i] *= corr[i];
      }
#pragma unroll
      for (int i = 0; i < 4; ++i)
#pragma unroll
        for (int u = 0; u < 4; ++u)
          P[(quad * 4 + i) * PSTR + u * 16 + lcol] = f2h(p[u][i]);
      f16x8 pf0 = *(const f16x8*)&P[lcol * PSTR + quad * 8];
      lacc = __builtin_amdgcn_mfma_f32_16x16x32_f16(pf0, onesv, lacc, 0, 0, 0);
      f16x8 va0 = *(const f16x8*)&Vt[lcol * VTSTR + k0 + quad * 8];
      f16x8 vb0 = *(const f16x8*)&Vt[(16 + lcol) * VTSTR + k0 + quad * 8];
      accA = __builtin_amdgcn_mfma_f32_16x16x32_f16(pf0, va0, accA, 0, 0, 0);
      accB = __builtin_amdgcn_mfma_f32_16x16x32_f16(pf0, vb0, accB, 0, 0, 0);
      if (full) {
        f16x8 pf1 = *(const f16x8*)&P[lcol * PSTR + 32 + quad * 8];
        lacc = __builtin_amdgcn_mfma_f32_16x16x32_f16(pf1, onesv, lacc, 0, 0, 0);
        f16x8 va1 = *(const f16x8*)&Vt[lcol * VTSTR + k0 + 32 + quad * 8];
        f16x8 vb1 = *(const f16x8*)&Vt[(16 + lcol) * VTSTR + k0 + 32 + quad * 8];
        accA = __builtin_amdgcn_mfma_f32_16x16x32_f16(pf1, va1, accA, 0, 0, 0);
        accB = __builtin_amdgcn_mfma_f32_16x16x32_f16(pf1, vb1, accB, 0, 0, 0);
      }
    }

#pragma unroll
    for (int i = 0; i < 4; ++i) {
      float inv = 1.f / lacc[i];
      P[(quad * 4 + i) * PSTR + lcol] = f2h(accA[i] * inv);
      P[(quad * 4 + i) * PSTR + 16 + lcol] = f2h(accB[i] * inv);
    }
    int row = lane >> 2, seg = lane & 3;
    f16x8 ov = *(const f16x8*)&P[row * PSTR + seg * 8];
    *(f16x8*)&O16[base + (size_t)(qb + row) * DD + seg * 8] = ov;
  }
}

// ---------------- MEGA var stage (32 rows/block, 8 waves) + fused next-QKV -
// grid 168 x 512thr; R3-verified. On the LAST iter (doqkv=0) also writes
// Et16 (f16 of final LN) -- the MFMA projection's A operand.
__global__ __launch_bounds__(512) void k_mega_var(
    const _Float16* __restrict__ AO16, const _Float16* __restrict__ WT2,
    const float* __restrict__ bq, const float* __restrict__ bk,
    const float* __restrict__ bv, const float* __restrict__ bo,
    const float* __restrict__ g1, const float* __restrict__ c1,
    const float* __restrict__ gn, const float* __restrict__ bn,
    float* __restrict__ Etime, _Float16* __restrict__ Q16,
    _Float16* __restrict__ K16, _Float16* __restrict__ V16,
    _Float16* __restrict__ Et16, int doqkv) {
  int tid = threadIdx.x;
  int wave = tid >> 6, lane = tid & 63;
  int quad = lane >> 4, lcol = lane & 15;

  __shared__ int rmapS[32];
  __shared__ _Float16 Af[32 * 264];    // 16.5 KB
  __shared__ float Cf[32 * 260];       // 33.3 KB
  __shared__ _Float16 QKVs[32 * 776];  // 48.5 KB

  if (tid < 32) {
    int r2 = blockIdx.x * 32 + tid;
    int n_idx = r2 >> 3, v = r2 & 7;
    int b = n_idx / SS, s = n_idx - b * SS;
    rmapS[tid] = (b * VV + v) * SS + s;
  }
  __syncthreads();

  // stage AO rows (time layout, gathered) into Af
  {
    int row = tid >> 4, seg = tid & 15;
    const _Float16* src = AO16 + (size_t)rmapS[row] * DD + seg * 16;
    _Float16* dst = Af + row * 264 + seg * 16;
    *(f16x8*)(dst) = *(const f16x8*)(src);
    *(f16x8*)(dst + 8) = *(const f16x8*)(src + 8);
  }
  __syncthreads();

  const _Float16* WoF = WT2 + (size_t)3 * 65536;   // Wo frag block

  // ---- time O-proj: Cf = Af @ Wo + bo + Etime(res) ----
  {
    f32x4 acc[2][2] = {};
    for (int kb = 0; kb < 8; ++kb) {
      int k0 = kb * 32;
      f16x8 af0 = *(const f16x8*)&Af[lcol * 264 + k0 + quad * 8];
      f16x8 af1 = *(const f16x8*)&Af[(16 + lcol) * 264 + k0 + quad * 8];
#pragma unroll
      for (int nt = 0; nt < 2; ++nt) {
        f16x8 bfr = *(const f16x8*)&WoF[((wave * 2 + nt) * 8 + kb) * 512 + lane * 8];
        acc[0][nt] = __builtin_amdgcn_mfma_f32_16x16x32_f16(af0, bfr, acc[0][nt], 0, 0, 0);
        acc[1][nt] = __builtin_amdgcn_mfma_f32_16x16x32_f16(af1, bfr, acc[1][nt], 0, 0, 0);
      }
    }
#pragma unroll
    for (int mt = 0; mt < 2; ++mt) {
#pragma unroll
      for (int i = 0; i < 4; ++i) {
        int row = mt * 16 + quad * 4 + i;
        size_t rb = (size_t)rmapS[row] * 256;
#pragma unroll
        for (int nt = 0; nt < 2; ++nt) {
          int col = (wave * 2 + nt) * 16 + lcol;
          Cf[row * 260 + col] = acc[mt][nt][i] + bo[col] + Etime[rb + col];
        }
      }
    }
  }
  __syncthreads();

  // ---- double LN (ln1 then norm); write Cf fp32 + Af f16 ----
  {
    int row = tid >> 4, c0 = (tid & 15) * 16;
    float v[16];
#pragma unroll
    for (int j = 0; j < 16; ++j) v[j] = Cf[row * 260 + c0 + j];
#pragma unroll
    for (int pass = 0; pass < 2; ++pass) {
      const float* gg = pass ? gn : g1;
      const float* bb = pass ? bn : c1;
      float s = 0.f, q = 0.f;
#pragma unroll
      for (int j = 0; j < 16; ++j) { s += v[j]; q = fmaf(v[j], v[j], q); }
      s += __shfl_xor(s, 1); q += __shfl_xor(q, 1);
      s += __shfl_xor(s, 2); q += __shfl_xor(q, 2);
      s += __shfl_xor(s, 4); q += __shfl_xor(q, 4);
      s += __shfl_xor(s, 8); q += __shfl_xor(q, 8);
      float mu = s * (1.0f / 256.0f);
      float rs = rsqrtf(q * (1.0f / 256.0f) - mu * mu + LN_EPS);
#pragma unroll
      for (int j = 0; j < 16; ++j)
        v[j] = fmaf((v[j] - mu) * rs, gg[c0 + j], bb[c0 + j]);
    }
#pragma unroll
    for (int j = 0; j < 16; ++j) Cf[row * 260 + c0 + j] = v[j];
#pragma unroll
    for (int j8 = 0; j8 < 2; ++j8) {
      f16x8 h;
#pragma unroll
      for (int jj = 0; jj < 8; ++jj) h[jj] = f2h(v[j8 * 8 + jj]);
      *(f16x8*)&Af[row * 264 + c0 + j8 * 8] = h;
    }
  }
  __syncthreads();

  // ---- var QKV: QKVs[32][768] = Af @ {Wq|Wk|Wv} + bias ----
  {
    f32x4 acc[2][6] = {};
    for (int kb = 0; kb < 8; ++kb) {
      int k0 = kb * 32;
      f16x8 af0 = *(const f16x8*)&Af[lcol * 264 + k0 + quad * 8];
      f16x8 af1 = *(const f16x8*)&Af[(16 + lcol) * 264 + k0 + quad * 8];
#pragma unroll
      for (int j = 0; j < 6; ++j) {
        int ntg = wave * 6 + j;                   // 0..47 == z*16 + ntile
        f16x8 bfr = *(const f16x8*)&WT2[(size_t)(ntg * 8 + kb) * 512 + lane * 8];
        acc[0][j] = __builtin_amdgcn_mfma_f32_16x16x32_f16(af0, bfr, acc[0][j], 0, 0, 0);
        acc[1][j] = __builtin_amdgcn_mfma_f32_16x16x32_f16(af1, bfr, acc[1][j], 0, 0, 0);
      }
    }
#pragma unroll
    for (int j = 0; j < 6; ++j) {
      int ntg = wave * 6 + j;
      int colb = ntg * 16;
      int z = colb >> 8, coln = (colb & 255) + lcol;
      const float* bz = (z == 0) ? bq : (z == 1) ? bk : bv;
      float bval = bz[coln];
#pragma unroll
      for (int mt = 0; mt < 2; ++mt) {
#pragma unroll
        for (int i = 0; i < 4; ++i)
          QKVs[(mt * 16 + quad * 4 + i) * 776 + colb + lcol] = f2h(acc[mt][j][i] + bval);
      }
    }
  }
  __syncthreads();

  // ---- var attention: all 512 thr; thread pairs split the 32 dims ----
  {
    int half = tid & 1, qi = (tid >> 1) & 7, h = (tid >> 4) & 7, ng = tid >> 7;
    int d0 = h * 32 + half * 16;
    const _Float16* Qp = &QKVs[(ng * 8 + qi) * 776 + d0];
    float qv[16];
#pragma unroll
    for (int j8 = 0; j8 < 2; ++j8) {
      f16x8 t = *(const f16x8*)(Qp + j8 * 8);
#pragma unroll
      for (int jj = 0; jj < 8; ++jj) qv[j8 * 8 + jj] = (float)t[jj];
    }
    float sc[8];
#pragma unroll
    for (int k = 0; k < 8; ++k) {
      const _Float16* Kp = &QKVs[(ng * 8 + k) * 776 + 256 + d0];
      float s = 0.f;
#pragma unroll
      for (int j8 = 0; j8 < 2; ++j8) {
        f16x8 t = *(const f16x8*)(Kp + j8 * 8);
#pragma unroll
        for (int jj = 0; jj < 8; ++jj) s = fmaf(qv[j8 * 8 + jj], (float)t[jj], s);
      }
      sc[k] = s;
    }
#pragma unroll
    for (int k = 0; k < 8; ++k)
      sc[k] = (sc[k] + __shfl_xor(sc[k], 1)) * ATT_SCALE;
    float mx = sc[0];
#pragma unroll
    for (int k = 1; k < 8; ++k) mx = fmaxf(mx, sc[k]);
    float ps = 0.f;
#pragma unroll
    for (int k = 0; k < 8; ++k) { sc[k] = __expf(sc[k] - mx); ps += sc[k]; }
    float inv = 1.f / ps;
    float ov[16];
#pragma unroll
    for (int j = 0; j < 16; ++j) ov[j] = 0.f;
#pragma unroll
    for (int k = 0; k < 8; ++k) {
      const _Float16* Vp = &QKVs[(ng * 8 + k) * 776 + 512 + d0];
      float p = sc[k];
#pragma unroll
      for (int j8 = 0; j8 < 2; ++j8) {
        f16x8 t = *(const f16x8*)(Vp + j8 * 8);
#pragma unroll
        for (int jj = 0; jj < 8; ++jj)
          ov[j8 * 8 + jj] = fmaf(p, (float)t[jj], ov[j8 * 8 + jj]);
      }
    }
    _Float16* Op = &Af[(ng * 8 + qi) * 264 + d0];
#pragma unroll
    for (int j8 = 0; j8 < 2; ++j8) {
      f16x8 hh;
#pragma unroll
      for (int jj = 0; jj < 8; ++jj) hh[jj] = f2h(ov[j8 * 8 + jj] * inv);
      *(f16x8*)(Op + j8 * 8) = hh;
    }
  }
  __syncthreads();

  // ---- var O-proj: Cf = Af @ Wo + bo + Cf(res x_var) ----
  {
    f32x4 acc[2][2] = {};
    for (int kb = 0; kb < 8; ++kb) {
      int k0 = kb * 32;
      f16x8 af0 = *(const f16x8*)&Af[lcol * 264 + k0 + quad * 8];
      f16x8 af1 = *(const f16x8*)&Af[(16 + lcol) * 264 + k0 + quad * 8];
#pragma unroll
      for (int nt = 0; nt < 2; ++nt) {
        f16x8 bfr = *(const f16x8*)&WoF[((wave * 2 + nt) * 8 + kb) * 512 + lane * 8];
        acc[0][nt] = __builtin_amdgcn_mfma_f32_16x16x32_f16(af0, bfr, acc[0][nt], 0, 0, 0);
        acc[1][nt] = __builtin_amdgcn_mfma_f32_16x16x32_f16(af1, bfr, acc[1][nt], 0, 0, 0);
      }
    }
#pragma unroll
    for (int mt = 0; mt < 2; ++mt) {
#pragma unroll
      for (int i = 0; i < 4; ++i) {
        int row = mt * 16 + quad * 4 + i;
#pragma unroll
        for (int nt = 0; nt < 2; ++nt) {
          int col = (wave * 2 + nt) * 16 + lcol;
          Cf[row * 260 + col] = acc[mt][nt][i] + bo[col] + Cf[row * 260 + col];
        }
      }
    }
  }
  __syncthreads();

  // ---- final LN1 + store Etime (f32) + Af (f16) [+ Et16 on last iter] ----
  {
    int row = tid >> 4, c0 = (tid & 15) * 16;
    float v[16];
#pragma unroll
    for (int j = 0; j < 16; ++j) v[j] = Cf[row * 260 + c0 + j];
    float s = 0.f, q = 0.f;
#pragma unroll
    for (int j = 0; j < 16; ++j) { s += v[j]; q = fmaf(v[j], v[j], q); }
    s += __shfl_xor(s, 1); q += __shfl_xor(q, 1);
    s += __shfl_xor(s, 2); q += __shfl_xor(q, 2);
    s += __shfl_xor(s, 4); q += __shfl_xor(q, 4);
    s += __shfl_xor(s, 8); q += __shfl_xor(q, 8);
    float mu = s * (1.0f / 256.0f);
    float rs = rsqrtf(q * (1.0f / 256.0f) - mu * mu + LN_EPS);
#pragma unroll
    for (int j = 0; j < 16; ++j)
      v[j] = fmaf((v[j] - mu) * rs, g1[c0 + j], c1[c0 + j]);
    size_t rb = (size_t)rmapS[row] * 256 + c0;
#pragma unroll
    for (int j4 = 0; j4 < 4; ++j4) {
      float4 f4 = make_float4(v[j4 * 4], v[j4 * 4 + 1], v[j4 * 4 + 2], v[j4 * 4 + 3]);
      *(float4*)&Etime[rb + j4 * 4] = f4;
    }
#pragma unroll
    for (int j8 = 0; j8 < 2; ++j8) {
      f16x8 hh;
#pragma unroll
      for (int jj = 0; jj < 8; ++jj) hh[jj] = f2h(v[j8 * 8 + jj]);
      *(f16x8*)&Af[row * 264 + c0 + j8 * 8] = hh;
      if (!doqkv) *(f16x8*)&Et16[rb + j8 * 8] = hh;
    }
  }
  __syncthreads();

  // ---- fused next-iteration time-stage QKV (skipped on last iter) ----
  if (doqkv) {
    f32x4 acc[2][6] = {};
    for (int kb = 0; kb < 8; ++kb) {
      int k0 = kb * 32;
      f16x8 af0 = *(const f16x8*)&Af[lcol * 264 + k0 + quad * 8];
      f16x8 af1 = *(const f16x8*)&Af[(16 + lcol) * 264 + k0 + quad * 8];
#pragma unroll
      for (int j = 0; j < 6; ++j) {
        int ntg = wave * 6 + j;                   // 0..47 == z*16 + ntile
        f16x8 bfr = *(const f16x8*)&WT2[(size_t)(ntg * 8 + kb) * 512 + lane * 8];
        acc[0][j] = __builtin_amdgcn_mfma_f32_16x16x32_f16(af0, bfr, acc[0][j], 0, 0, 0);
        acc[1][j] = __builtin_amdgcn_mfma_f32_16x16x32_f16(af1, bfr, acc[1][j], 0, 0, 0);
      }
    }
#pragma unroll
    for (int j = 0; j < 6; ++j) {
      int ntg = wave * 6 + j;
      int colb = ntg * 16;
      int z = colb >> 8, coln = (colb & 255) + lcol;
      const float* bz = (z == 0) ? bq : (z == 1) ? bk : bv;
      _Float16* Hd = (z == 0) ? Q16 : (z == 1) ? K16 : V16;
      float bval = bz[coln];
#pragma unroll
      for (int mt = 0; mt < 2; ++mt) {
#pragma unroll
        for (int i = 0; i < 4; ++i) {
          int row = mt * 16 + quad * 4 + i;
          Hd[(size_t)rmapS[row] * 256 + coln] = f2h(acc[mt][j][i] + bval);
        }
      }
    }
  }
}

// ---------------- final projection: MFMA over f16 (single node) -------------
// 336 blocks x 512 thr (8 waves). Block owns 8 ktiles (256 k). Stage Et16
// rows (stride-264, 8.25KB) + PWF slice (48KB linear, 6 back-to-back 16B
// loads/thread = deep MLP -> BW-bound stream of 16.5MB total). Wave w<6 owns
// n-tile w: 8 MFMAs over the 256-k chunk; commit 4 f32 atomics/lane (516K
// total). out pre-seeded with bias by k_init. LDS 57KB -> 2 blocks/CU.
__global__ __launch_bounds__(512) void k_proj(
    const _Float16* __restrict__ Et16, const _Float16* __restrict__ PWF,
    float* __restrict__ out) {
  __shared__ _Float16 Ets[16 * 264];       // 8.25 KB
  __shared__ _Float16 PWFs[8 * 6 * 512];   // 48 KB
  int tid = threadIdx.x;
  int wave = tid >> 6, lane = tid & 63;
  int quad = lane >> 4, lcol = lane & 15;
  int kt0 = blockIdx.x * 8;                // global ktile base
  size_t kc0 = (size_t)kt0 * 32;

  {
    int r = tid >> 5, seg = tid & 31;
    *(f16x8*)&Ets[r * 264 + seg * 8] =
        *(const f16x8*)&Et16[(size_t)r * 86016 + kc0 + seg * 8];
  }
  {
    const _Float16* src = PWF + (size_t)kt0 * 6 * 512;
#pragma unroll
    for (int i = 0; i < 6; ++i) {
      int g = i * 512 + tid;               // 3072 f16x8 groups
      *(f16x8*)&PWFs[g * 8] = *(const f16x8*)&src[(size_t)g * 8];
    }
  }
  __syncthreads();

  if (wave < 6) {
    f32x4 acc = {0.f, 0.f, 0.f, 0.f};
#pragma unroll
    for (int kt = 0; kt < 8; ++kt) {
      f16x8 af = *(const f16x8*)&Ets[lcol * 264 + kt * 32 + quad * 8];
      f16x8 bf = *(const f16x8*)&PWFs[((kt * 6 + wave) << 9) + lane * 8];
      acc = __builtin_amdgcn_mfma_f32_16x16x32_f16(af, bf, acc, 0, 0, 0);
    }
    int col = wave * 16 + lcol;
#pragma unroll
    for (int i = 0; i < 4; ++i) {
      int r = quad * 4 + i;
      atomicAdd(&out[(r >> 3) * 768 + col * 8 + (r & 7)], acc[i]);
    }
  }
}

// ---------------- launch ---------------------------------------------------
extern "C" void kernel_launch(void* const* d_in, const int* in_sizes, int n_in,
                              void* d_out, int out_size, void* d_ws,
                              size_t ws_size, hipStream_t stream) {
  const float* x     = (const float*)d_in[0];
  const float* emb_w = (const float*)d_in[1];
  const float* emb_b = (const float*)d_in[2];
  const float* Wq = (const float*)d_in[3];
  const float* bq = (const float*)d_in[4];
  const float* Wk = (const float*)d_in[5];
  const float* bk = (const float*)d_in[6];
  const float* Wv = (const float*)d_in[7];
  const float* bv = (const float*)d_in[8];
  const float* Wo = (const float*)d_in[9];
  const float* bo = (const float*)d_in[10];
  const float* g1 = (const float*)d_in[11];
  const float* b1 = (const float*)d_in[12];
  const float* gn = (const float*)d_in[13];
  const float* bn = (const float*)d_in[14];
  const float* PW = (const float*)d_in[15];
  const float* PB = (const float*)d_in[16];
  float* out = (float*)d_out;

  float* ws = (float*)d_ws;
  float* Etime   = ws;                              // NTD f32
  _Float16* Et16 = (_Float16*)(ws + (size_t)NTD);   // NTD f16
  _Float16* Q16  = (_Float16*)(ws + (size_t)NTD + NTD / 2);
  _Float16* K16  = Q16 + (size_t)NTD;
  _Float16* V16  = K16 + (size_t)NTD;
  _Float16* AO16 = V16 + (size_t)NTD;
  _Float16* WT2  = AO16 + (size_t)NTD;              // 4*65536 f16 (frag order)
  _Float16* PWF  = WT2 + 4 * 65536;                 // 8.25M f16 (proj frags)

  k_init<<<10432, 256, 0, stream>>>(Wq, Wk, Wv, Wo, x, emb_w, emb_b, PB, PW,
                                    WT2, Etime, Et16, PWF, out);
  for (int it = 0; it < 10; ++it) {
    k_attn_time<<<dim3(2, 8, 16), 512, 0, stream>>>(
        Et16, Q16, K16, V16, WT2, bq, bk, bv, AO16, (it == 0) ? 1 : 0);
    k_mega_var<<<168, 512, 0, stream>>>(
        AO16, WT2, bq, bk, bv, bo, g1, b1, gn, bn, Etime,
        Q16, K16, V16, Et16, (it < 9) ? 1 : 0);
  }
  k_proj<<<336, 512, 0, stream>>>(Et16, PWF, out);
}

// Round 10
// 553.688 us; speedup vs baseline: 1.1122x; 1.0450x over previous
//
#include <hip/hip_runtime.h>

#define SS 336
#define VV 8
#define DD 256
#define DKK 32
#define NTOK 5376            // B*V*S = B*S*V tokens
#define NTD (NTOK * DD)      // 1376256 elements per activation buffer
#define ATT_SCALE 0.17677669529663687f  // 1/sqrt(32)
#define LN_EPS 1e-5f

typedef _Float16 f16x8 __attribute__((ext_vector_type(8)));
typedef _Float16 f16x4v __attribute__((ext_vector_type(4)));
typedef __attribute__((ext_vector_type(4))) float f32x4;

__device__ inline _Float16 f2h(float f) { return (_Float16)f; }

// ---------------- fused init: W prep + embed + out=bias + PWF16 prep --------
// blocks 0..1023: WT2 frag prep. 1024..6399: embed. 6400..10431: PWF16 prep
// (proj weight in MFMA B-frag order, f16 -> halves the k_proj stream).
// PWF offset(ktile,nt,lane,j) = ((ktile*6+nt)*64+lane)*8+j holds
// PW[k][n] with k = ktile*32 + (lane>>4)*8 + j, n = nt*16 + (lane&15).
__global__ __launch_bounds__(256) void k_init(
    const float* __restrict__ Wq, const float* __restrict__ Wk,
    const float* __restrict__ Wv, const float* __restrict__ Wo,
    const float* __restrict__ x, const float* __restrict__ ew,
    const float* __restrict__ eb, const float* __restrict__ PB,
    const float* __restrict__ PW,
    _Float16* __restrict__ WT2, float* __restrict__ E,
    _Float16* __restrict__ E16, _Float16* __restrict__ PWF,
    float* __restrict__ out) {
  int bid = blockIdx.x;
  int tid = threadIdx.x;
  if (bid < 1024) {
    int z = bid >> 8;
    const float* W = (z == 0) ? Wq : (z == 1) ? Wk : (z == 2) ? Wv : Wo;
    int o = (bid & 255) * 256 + tid;          // 0..65535
    int blk = o >> 9;                          // ntile*8 + kb
    int idx = o & 511;
    int lane = idx >> 3, j = idx & 7;
    int nt = blk >> 3, kb = blk & 7;
    int lcol = lane & 15, quad = lane >> 4;
    int n = nt * 16 + lcol;
    int k = kb * 32 + quad * 8 + j;
    WT2[(size_t)z * 65536 + o] = f2h(W[k * 256 + n]);
    if (bid == 0) {
      for (int i = tid; i < 1536; i += 256) {
        int row = i / 96, p = i - row * 96;
        out[(row >> 3) * 768 + p * 8 + (row & 7)] = PB[p];
      }
    }
  } else if (bid < 6400) {
    int token = bid - 1024;            // (b*V+v)*S + s
    int n = token / SS, s = token - n * SS;
    int b = n >> 3, v = n & 7;
    float xv = x[(b * SS + s) * VV + v];
    int d = tid;
    float val = fmaf(xv, ew[d], eb[d]);
    E[token * DD + d] = val;
    E16[token * DD + d] = f2h(val);
  } else {
    int idx = (bid - 6400) * 256 + tid;  // 0..1032191 = 2688 ktiles * 6 nt * 64
    int ktile = idx / 384;
    int rem = idx - ktile * 384;
    int nt = rem >> 6, lane = rem & 63;
    int quad = lane >> 4, lcol = lane & 15;
    int k0 = ktile * 32 + quad * 8;
    int n = nt * 16 + lcol;
    f16x8 w;
#pragma unroll
    for (int j = 0; j < 8; ++j) w[j] = f2h(PW[(size_t)(k0 + j) * 96 + n]);
    *(f16x8*)&PWF[(size_t)idx * 8] = w;
  }
}

// ---------------- time attention (mode0: QKV from global; mode1: in-LDS QKV)
// grid (2, 8, 16) = 256 blocks x 512 thr (8 waves).
#define KSTR 36
#define VTSTR 344
#define PSTR 72
#define QSTR 40
__global__ __launch_bounds__(512) void k_attn_time(
    const _Float16* __restrict__ Et16, const _Float16* __restrict__ Q16,
    const _Float16* __restrict__ K16, const _Float16* __restrict__ V16,
    const _Float16* __restrict__ WT2,
    const float* __restrict__ bq, const float* __restrict__ bk,
    const float* __restrict__ bv, _Float16* __restrict__ O16, int mode) {
  int qg = blockIdx.x, h = blockIdx.y, n = blockIdx.z;
  int tid = threadIdx.x;
  int wave = tid >> 6, lane = tid & 63;
  int quad = lane >> 4, lcol = lane & 15;

  __shared__ __align__(16) char SMRAW[143264];
  _Float16* Ks  = (_Float16*)SMRAW;
  _Float16* Vt  = (_Float16*)(SMRAW + 24192);
  _Float16* Qs  = (_Float16*)(SMRAW + 46240);
  _Float16* Wl  = (_Float16*)(SMRAW + 60320);
  _Float16* Ach = (_Float16*)(SMRAW + 109472);
  _Float16* PsB = (_Float16*)(mode ? SMRAW + 60320 : SMRAW + 46240);

  const size_t ebase = (size_t)(n * SS) * DD;
  const size_t base  = ebase + h * DKK;
  int qt0 = qg ? 11 : 0;
  int qtend = qg ? 21 : 11;

  const f32x4 z4 = {0.f, 0.f, 0.f, 0.f};

  if (mode) {
    // ---- QKV from Et16 (R5 path): W slices, then 6 m-chunks ----
    {
      int h2 = h * 2;
      for (int c = tid; c < 3072; c += 512) {
        int ot = c >> 9, rest = c & 511;
        int z = (ot < 2) ? 1 : (ot < 4) ? 2 : 0;
        int nt = h2 + (ot & 1);
        *(f16x8*)&Wl[(ot << 12) + rest * 8] =
            *(const f16x8*)&WT2[(size_t)z * 65536 + nt * 4096 + rest * 8];
      }
      for (int c = tid; c < 272; c += 512) {
        if (c < 256) {
          int d = c >> 3, col = 336 + (c & 7);
          Vt[d * VTSTR + col] = (_Float16)0.f;
        } else {
          Vt[32 * VTSTR + (c - 256)] = (_Float16)0.f;
        }
      }
    }
    for (int ck = 0; ck < 6; ++ck) {
      int m0c = ck * 64;
      int nmt = (ck < 5) ? 4 : 1;
      __syncthreads();
      for (int c = tid; c < nmt * 16 * 32; c += 512) {
        int row = c >> 5, seg = c & 31;
        *(f16x8*)&Ach[row * 264 + seg * 8] =
            *(const f16x8*)&Et16[ebase + (size_t)(m0c + row) * 256 + seg * 8];
      }
      __syncthreads();
      int nU = nmt * 6;
      for (int u = wave; u < nU; u += 8) {
        int mtl = u / 6, ot = u % 6;
        int gt = ck * 4 + mtl;
        if (ot >= 4 && (gt < qt0 || gt >= qtend)) continue;
        f32x4 acc = z4;
#pragma unroll
        for (int kb = 0; kb < 8; ++kb) {
          f16x8 af = *(const f16x8*)&Ach[(mtl * 16 + lcol) * 264 + kb * 32 + quad * 8];
          f16x8 wf = *(const f16x8*)&Wl[(ot << 12) + kb * 512 + lane * 8];
          acc = __builtin_amdgcn_mfma_f32_16x16x32_f16(af, wf, acc, 0, 0, 0);
        }
        int dlo = ((ot & 1) << 4) + lcol;
        const float* bz = (ot < 2) ? bk : (ot < 4) ? bv : bq;
        float bval = bz[h * 32 + dlo];
        if (ot < 2) {
#pragma unroll
          for (int i = 0; i < 4; ++i)
            Ks[(m0c + mtl * 16 + quad * 4 + i) * KSTR + dlo] = f2h(acc[i] + bval);
        } else if (ot < 4) {
#pragma unroll
          for (int i = 0; i < 4; ++i)
            Vt[dlo * VTSTR + (m0c + mtl * 16 + quad * 4 + i)] = f2h(acc[i] + bval);
        } else {
          int ql = gt - qt0;
#pragma unroll
          for (int i = 0; i < 4; ++i)
            Qs[(ql * 16 + quad * 4 + i) * QSTR + dlo] = f2h(acc[i] + bval);
        }
      }
    }
    __syncthreads();   // Ks/Vt/Qs ready; Wl/Ach dead -> Ps may overlay
  } else {
    // ---- stage K/V from global (R3 path) ----
    for (int c = tid; c < 1344; c += 512) {
      int row = c >> 2, part = c & 3;
      f16x8 kv = *(const f16x8*)&K16[base + (size_t)row * DD + part * 8];
      f16x4v klo = __builtin_shufflevector(kv, kv, 0, 1, 2, 3);
      f16x4v khi = __builtin_shufflevector(kv, kv, 4, 5, 6, 7);
      *(f16x4v*)&Ks[row * KSTR + part * 8] = klo;
      *(f16x4v*)&Ks[row * KSTR + part * 8 + 4] = khi;
      f16x8 vv = *(const f16x8*)&V16[base + (size_t)row * DD + part * 8];
#pragma unroll
      for (int j = 0; j < 8; ++j) Vt[(part * 8 + j) * VTSTR + row] = vv[j];
    }
    for (int c = tid; c < 272; c += 512) {
      if (c < 256) {
        int d = c >> 3, col = 336 + (c & 7);
        Vt[d * VTSTR + col] = (_Float16)0.f;
      } else {
        Vt[32 * VTSTR + (c - 256)] = (_Float16)0.f;
      }
    }
    __syncthreads();
  }

  // ---- flash attention over 336 keys (KVBLK=64, R3-verified) ----
  _Float16* P = PsB + wave * (16 * PSTR);
  const f16x8 onesv = {(_Float16)1.f, (_Float16)1.f, (_Float16)1.f, (_Float16)1.f,
                       (_Float16)1.f, (_Float16)1.f, (_Float16)1.f, (_Float16)1.f};

  for (int qtile = qt0 + wave; qtile < qtend; qtile += 8) {
    int qb = qtile * 16;
    int ql = qtile - qt0;

    f16x8 qf;
    if (mode)
      qf = *(const f16x8*)&Qs[(ql * 16 + lcol) * QSTR + quad * 8];
    else
      qf = *(const f16x8*)&Q16[base + (size_t)(qb + lcol) * DD + quad * 8];
    f32x4 accA = {0.f, 0.f, 0.f, 0.f};
    f32x4 accB = {0.f, 0.f, 0.f, 0.f};
    f32x4 lacc = {0.f, 0.f, 0.f, 0.f};
    float m_[4] = {-1e30f, -1e30f, -1e30f, -1e30f};

    // 336 = 5*64 + 16: T=0..4 full 64-key blocks, T=5 tail (16 keys)
    for (int T = 0; T < 6; ++T) {
      int k0 = T * 64;
      bool full = (T < 5);
      f32x4 s[4];
      {
        const _Float16* kp = &Ks[(k0 + lcol) * KSTR + quad * 8];
        f16x4v a0 = *(const f16x4v*)kp;
        f16x4v b0 = *(const f16x4v*)(kp + 4);
        f16x8 kf = __builtin_shufflevector(a0, b0, 0, 1, 2, 3, 4, 5, 6, 7);
        s[0] = __builtin_amdgcn_mfma_f32_16x16x32_f16(qf, kf, z4, 0, 0, 0);
      }
      if (full) {
#pragma unroll
        for (int u = 1; u < 4; ++u) {
          const _Float16* kp = &Ks[(k0 + u * 16 + lcol) * KSTR + quad * 8];
          f16x4v a0 = *(const f16x4v*)kp;
          f16x4v b0 = *(const f16x4v*)(kp + 4);
          f16x8 kf = __builtin_shufflevector(a0, b0, 0, 1, 2, 3, 4, 5, 6, 7);
          s[u] = __builtin_amdgcn_mfma_f32_16x16x32_f16(qf, kf, z4, 0, 0, 0);
        }
      } else {
        s[1] = z4; s[2] = z4; s[3] = z4;
      }
      float sc[4][4], p[4][4], corr[4];
#pragma unroll
      for (int u = 0; u < 4; ++u)
#pragma unroll
        for (int i = 0; i < 4; ++i)
          sc[u][i] = (u == 0 || full) ? s[u][i] * ATT_SCALE : -1e30f;
#pragma unroll
      for (int i = 0; i < 4; ++i) {
        float t2 = fmaxf(fmaxf(sc[0][i], sc[1][i]), fmaxf(sc[2][i], sc[3][i]));
        t2 = fmaxf(t2, __shfl_xor(t2, 1));
        t2 = fmaxf(t2, __shfl_xor(t2, 2));
        t2 = fmaxf(t2, __shfl_xor(t2, 4));
        t2 = fmaxf(t2, __shfl_xor(t2, 8));
        float nm = fmaxf(m_[i], t2);
        corr[i] = __expf(m_[i] - nm);
        m_[i] = nm;
#pragma unroll
        for (int u = 0; u < 4; ++u) p[u][i] = __expf(sc[u][i] - nm);
        accA[i] *= corr[i];
        accB[i] *= corr[i];
        lacc[i] *= corr[i];
      }
#pragma unroll
      for (int i = 0; i < 4; ++i)
#pragma unroll
        for (int u = 0; u < 4; ++u)
          P[(quad * 4 + i) * PSTR + u * 16 + lcol] = f2h(p[u][i]);
      f16x8 pf0 = *(const f16x8*)&P[lcol * PSTR + quad * 8];
      lacc = __builtin_amdgcn_mfma_f32_16x16x32_f16(pf0, onesv, lacc, 0, 0, 0);
      f16x8 va0 = *(const f16x8*)&Vt[lcol * VTSTR + k0 + quad * 8];
      f16x8 vb0 = *(const f16x8*)&Vt[(16 + lcol) * VTSTR + k0 + quad * 8];
      accA = __builtin_amdgcn_mfma_f32_16x16x32_f16(pf0, va0, accA, 0, 0, 0);
      accB = __builtin_amdgcn_mfma_f32_16x16x32_f16(pf0, vb0, accB, 0, 0, 0);
      if (full) {
        f16x8 pf1 = *(const f16x8*)&P[lcol * PSTR + 32 + quad * 8];
        lacc = __builtin_amdgcn_mfma_f32_16x16x32_f16(pf1, onesv, lacc, 0, 0, 0);
        f16x8 va1 = *(const f16x8*)&Vt[lcol * VTSTR + k0 + 32 + quad * 8];
        f16x8 vb1 = *(const f16x8*)&Vt[(16 + lcol) * VTSTR + k0 + 32 + quad * 8];
        accA = __builtin_amdgcn_mfma_f32_16x16x32_f16(pf1, va1, accA, 0, 0, 0);
        accB = __builtin_amdgcn_mfma_f32_16x16x32_f16(pf1, vb1, accB, 0, 0, 0);
      }
    }

#pragma unroll
    for (int i = 0; i < 4; ++i) {
      float inv = 1.f / lacc[i];
      P[(quad * 4 + i) * PSTR + lcol] = f2h(accA[i] * inv);
      P[(quad * 4 + i) * PSTR + 16 + lcol] = f2h(accB[i] * inv);
    }
    int row = lane >> 2, seg = lane & 3;
    f16x8 ov = *(const f16x8*)&P[row * PSTR + seg * 8];
    *(f16x8*)&O16[base + (size_t)(qb + row) * DD + seg * 8] = ov;
  }
}

// ---------------- MEGA var stage (32 rows/block, 8 waves) + fused next-QKV -
// grid 168 x 512thr; R3-verified. On the LAST iter (doqkv=0) also writes
// Et16 (f16 of final LN) -- the MFMA projection's A operand.
__global__ __launch_bounds__(512) void k_mega_var(
    const _Float16* __restrict__ AO16, const _Float16* __restrict__ WT2,
    const float* __restrict__ bq, const float* __restrict__ bk,
    const float* __restrict__ bv, const float* __restrict__ bo,
    const float* __restrict__ g1, const float* __restrict__ c1,
    const float* __restrict__ gn, const float* __restrict__ bn,
    float* __restrict__ Etime, _Float16* __restrict__ Q16,
    _Float16* __restrict__ K16, _Float16* __restrict__ V16,
    _Float16* __restrict__ Et16, int doqkv) {
  int tid = threadIdx.x;
  int wave = tid >> 6, lane = tid & 63;
  int quad = lane >> 4, lcol = lane & 15;

  __shared__ int rmapS[32];
  __shared__ _Float16 Af[32 * 264];    // 16.5 KB
  __shared__ float Cf[32 * 260];       // 33.3 KB
  __shared__ _Float16 QKVs[32 * 776];  // 48.5 KB

  if (tid < 32) {
    int r2 = blockIdx.x * 32 + tid;
    int n_idx = r2 >> 3, v = r2 & 7;
    int b = n_idx / SS, s = n_idx - b * SS;
    rmapS[tid] = (b * VV + v) * SS + s;
  }
  __syncthreads();

  // stage AO rows (time layout, gathered) into Af
  {
    int row = tid >> 4, seg = tid & 15;
    const _Float16* src = AO16 + (size_t)rmapS[row] * DD + seg * 16;
    _Float16* dst = Af + row * 264 + seg * 16;
    *(f16x8*)(dst) = *(const f16x8*)(src);
    *(f16x8*)(dst + 8) = *(const f16x8*)(src + 8);
  }
  __syncthreads();

  const _Float16* WoF = WT2 + (size_t)3 * 65536;   // Wo frag block

  // ---- time O-proj: Cf = Af @ Wo + bo + Etime(res) ----
  {
    f32x4 acc[2][2] = {};
    for (int kb = 0; kb < 8; ++kb) {
      int k0 = kb * 32;
      f16x8 af0 = *(const f16x8*)&Af[lcol * 264 + k0 + quad * 8];
      f16x8 af1 = *(const f16x8*)&Af[(16 + lcol) * 264 + k0 + quad * 8];
#pragma unroll
      for (int nt = 0; nt < 2; ++nt) {
        f16x8 bfr = *(const f16x8*)&WoF[((wave * 2 + nt) * 8 + kb) * 512 + lane * 8];
        acc[0][nt] = __builtin_amdgcn_mfma_f32_16x16x32_f16(af0, bfr, acc[0][nt], 0, 0, 0);
        acc[1][nt] = __builtin_amdgcn_mfma_f32_16x16x32_f16(af1, bfr, acc[1][nt], 0, 0, 0);
      }
    }
#pragma unroll
    for (int mt = 0; mt < 2; ++mt) {
#pragma unroll
      for (int i = 0; i < 4; ++i) {
        int row = mt * 16 + quad * 4 + i;
        size_t rb = (size_t)rmapS[row] * 256;
#pragma unroll
        for (int nt = 0; nt < 2; ++nt) {
          int col = (wave * 2 + nt) * 16 + lcol;
          Cf[row * 260 + col] = acc[mt][nt][i] + bo[col] + Etime[rb + col];
        }
      }
    }
  }
  __syncthreads();

  // ---- double LN (ln1 then norm); write Cf fp32 + Af f16 ----
  {
    int row = tid >> 4, c0 = (tid & 15) * 16;
    float v[16];
#pragma unroll
    for (int j = 0; j < 16; ++j) v[j] = Cf[row * 260 + c0 + j];
#pragma unroll
    for (int pass = 0; pass < 2; ++pass) {
      const float* gg = pass ? gn : g1;
      const float* bb = pass ? bn : c1;
      float s = 0.f, q = 0.f;
#pragma unroll
      for (int j = 0; j < 16; ++j) { s += v[j]; q = fmaf(v[j], v[j], q); }
      s += __shfl_xor(s, 1); q += __shfl_xor(q, 1);
      s += __shfl_xor(s, 2); q += __shfl_xor(q, 2);
      s += __shfl_xor(s, 4); q += __shfl_xor(q, 4);
      s += __shfl_xor(s, 8); q += __shfl_xor(q, 8);
      float mu = s * (1.0f / 256.0f);
      float rs = rsqrtf(q * (1.0f / 256.0f) - mu * mu + LN_EPS);
#pragma unroll
      for (int j = 0; j < 16; ++j)
        v[j] = fmaf((v[j] - mu) * rs, gg[c0 + j], bb[c0 + j]);
    }
#pragma unroll
    for (int j = 0; j < 16; ++j) Cf[row * 260 + c0 + j] = v[j];
#pragma unroll
    for (int j8 = 0; j8 < 2; ++j8) {
      f16x8 h;
#pragma unroll
      for (int jj = 0; jj < 8; ++jj) h[jj] = f2h(v[j8 * 8 + jj]);
      *(f16x8*)&Af[row * 264 + c0 + j8 * 8] = h;
    }
  }
  __syncthreads();

  // ---- var QKV: QKVs[32][768] = Af @ {Wq|Wk|Wv} + bias ----
  {
    f32x4 acc[2][6] = {};
    for (int kb = 0; kb < 8; ++kb) {
      int k0 = kb * 32;
      f16x8 af0 = *(const f16x8*)&Af[lcol * 264 + k0 + quad * 8];
      f16x8 af1 = *(const f16x8*)&Af[(16 + lcol) * 264 + k0 + quad * 8];
#pragma unroll
      for (int j = 0; j < 6; ++j) {
        int ntg = wave * 6 + j;                   // 0..47 == z*16 + ntile
        f16x8 bfr = *(const f16x8*)&WT2[(size_t)(ntg * 8 + kb) * 512 + lane * 8];
        acc[0][j] = __builtin_amdgcn_mfma_f32_16x16x32_f16(af0, bfr, acc[0][j], 0, 0, 0);
        acc[1][j] = __builtin_amdgcn_mfma_f32_16x16x32_f16(af1, bfr, acc[1][j], 0, 0, 0);
      }
    }
#pragma unroll
    for (int j = 0; j < 6; ++j) {
      int ntg = wave * 6 + j;
      int colb = ntg * 16;
      int z = colb >> 8, coln = (colb & 255) + lcol;
      const float* bz = (z == 0) ? bq : (z == 1) ? bk : bv;
      float bval = bz[coln];
#pragma unroll
      for (int mt = 0; mt < 2; ++mt) {
#pragma unroll
        for (int i = 0; i < 4; ++i)
          QKVs[(mt * 16 + quad * 4 + i) * 776 + colb + lcol] = f2h(acc[mt][j][i] + bval);
      }
    }
  }
  __syncthreads();

  // ---- var attention: all 512 thr; thread pairs split the 32 dims ----
  {
    int half = tid & 1, qi = (tid >> 1) & 7, h = (tid >> 4) & 7, ng = tid >> 7;
    int d0 = h * 32 + half * 16;
    const _Float16* Qp = &QKVs[(ng * 8 + qi) * 776 + d0];
    float qv[16];
#pragma unroll
    for (int j8 = 0; j8 < 2; ++j8) {
      f16x8 t = *(const f16x8*)(Qp + j8 * 8);
#pragma unroll
      for (int jj = 0; jj < 8; ++jj) qv[j8 * 8 + jj] = (float)t[jj];
    }
    float sc[8];
#pragma unroll
    for (int k = 0; k < 8; ++k) {
      const _Float16* Kp = &QKVs[(ng * 8 + k) * 776 + 256 + d0];
      float s = 0.f;
#pragma unroll
      for (int j8 = 0; j8 < 2; ++j8) {
        f16x8 t = *(const f16x8*)(Kp + j8 * 8);
#pragma unroll
        for (int jj = 0; jj < 8; ++jj) s = fmaf(qv[j8 * 8 + jj], (float)t[jj], s);
      }
      sc[k] = s;
    }
#pragma unroll
    for (int k = 0; k < 8; ++k)
      sc[k] = (sc[k] + __shfl_xor(sc[k], 1)) * ATT_SCALE;
    float mx = sc[0];
#pragma unroll
    for (int k = 1; k < 8; ++k) mx = fmaxf(mx, sc[k]);
    float ps = 0.f;
#pragma unroll
    for (int k = 0; k < 8; ++k) { sc[k] = __expf(sc[k] - mx); ps += sc[k]; }
    float inv = 1.f / ps;
    float ov[16];
#pragma unroll
    for (int j = 0; j < 16; ++j) ov[j] = 0.f;
#pragma unroll
    for (int k = 0; k < 8; ++k) {
      const _Float16* Vp = &QKVs[(ng * 8 + k) * 776 + 512 + d0];
      float p = sc[k];
#pragma unroll
      for (int j8 = 0; j8 < 2; ++j8) {
        f16x8 t = *(const f16x8*)(Vp + j8 * 8);
#pragma unroll
        for (int jj = 0; jj < 8; ++jj)
          ov[j8 * 8 + jj] = fmaf(p, (float)t[jj], ov[j8 * 8 + jj]);
      }
    }
    _Float16* Op = &Af[(ng * 8 + qi) * 264 + d0];
#pragma unroll
    for (int j8 = 0; j8 < 2; ++j8) {
      f16x8 hh;
#pragma unroll
      for (int jj = 0; jj < 8; ++jj) hh[jj] = f2h(ov[j8 * 8 + jj] * inv);
      *(f16x8*)(Op + j8 * 8) = hh;
    }
  }
  __syncthreads();

  // ---- var O-proj: Cf = Af @ Wo + bo + Cf(res x_var) ----
  {
    f32x4 acc[2][2] = {};
    for (int kb = 0; kb < 8; ++kb) {
      int k0 = kb * 32;
      f16x8 af0 = *(const f16x8*)&Af[lcol * 264 + k0 + quad * 8];
      f16x8 af1 = *(const f16x8*)&Af[(16 + lcol) * 264 + k0 + quad * 8];
#pragma unroll
      for (int nt = 0; nt < 2; ++nt) {
        f16x8 bfr = *(const f16x8*)&WoF[((wave * 2 + nt) * 8 + kb) * 512 + lane * 8];
        acc[0][nt] = __builtin_amdgcn_mfma_f32_16x16x32_f16(af0, bfr, acc[0][nt], 0, 0, 0);
        acc[1][nt] = __builtin_amdgcn_mfma_f32_16x16x32_f16(af1, bfr, acc[1][nt], 0, 0, 0);
      }
    }
#pragma unroll
    for (int mt = 0; mt < 2; ++mt) {
#pragma unroll
      for (int i = 0; i < 4; ++i) {
        int row = mt * 16 + quad * 4 + i;
#pragma unroll
        for (int nt = 0; nt < 2; ++nt) {
          int col = (wave * 2 + nt) * 16 + lcol;
          Cf[row * 260 + col] = acc[mt][nt][i] + bo[col] + Cf[row * 260 + col];
        }
      }
    }
  }
  __syncthreads();

  // ---- final LN1 + store Etime (f32) + Af (f16) [+ Et16 on last iter] ----
  {
    int row = tid >> 4, c0 = (tid & 15) * 16;
    float v[16];
#pragma unroll
    for (int j = 0; j < 16; ++j) v[j] = Cf[row * 260 + c0 + j];
    float s = 0.f, q = 0.f;
#pragma unroll
    for (int j = 0; j < 16; ++j) { s += v[j]; q = fmaf(v[j], v[j], q); }
    s += __shfl_xor(s, 1); q += __shfl_xor(q, 1);
    s += __shfl_xor(s, 2); q += __shfl_xor(q, 2);
    s += __shfl_xor(s, 4); q += __shfl_xor(q, 4);
    s += __shfl_xor(s, 8); q += __shfl_xor(q, 8);
    float mu = s * (1.0f / 256.0f);
    float rs = rsqrtf(q * (1.0f / 256.0f) - mu * mu + LN_EPS);
#pragma unroll
    for (int j = 0; j < 16; ++j)
      v[j] = fmaf((v[j] - mu) * rs, g1[c0 + j], c1[c0 + j]);
    size_t rb = (size_t)rmapS[row] * 256 + c0;
#pragma unroll
    for (int j4 = 0; j4 < 4; ++j4) {
      float4 f4 = make_float4(v[j4 * 4], v[j4 * 4 + 1], v[j4 * 4 + 2], v[j4 * 4 + 3]);
      *(float4*)&Etime[rb + j4 * 4] = f4;
    }
#pragma unroll
    for (int j8 = 0; j8 < 2; ++j8) {
      f16x8 hh;
#pragma unroll
      for (int jj = 0; jj < 8; ++jj) hh[jj] = f2h(v[j8 * 8 + jj]);
      *(f16x8*)&Af[row * 264 + c0 + j8 * 8] = hh;
      if (!doqkv) *(f16x8*)&Et16[rb + j8 * 8] = hh;
    }
  }
  __syncthreads();

  // ---- fused next-iteration time-stage QKV (skipped on last iter) ----
  if (doqkv) {
    f32x4 acc[2][6] = {};
    for (int kb = 0; kb < 8; ++kb) {
      int k0 = kb * 32;
      f16x8 af0 = *(const f16x8*)&Af[lcol * 264 + k0 + quad * 8];
      f16x8 af1 = *(const f16x8*)&Af[(16 + lcol) * 264 + k0 + quad * 8];
#pragma unroll
      for (int j = 0; j < 6; ++j) {
        int ntg = wave * 6 + j;                   // 0..47 == z*16 + ntile
        f16x8 bfr = *(const f16x8*)&WT2[(size_t)(ntg * 8 + kb) * 512 + lane * 8];
        acc[0][j] = __builtin_amdgcn_mfma_f32_16x16x32_f16(af0, bfr, acc[0][j], 0, 0, 0);
        acc[1][j] = __builtin_amdgcn_mfma_f32_16x16x32_f16(af1, bfr, acc[1][j], 0, 0, 0);
      }
    }
#pragma unroll
    for (int j = 0; j < 6; ++j) {
      int ntg = wave * 6 + j;
      int colb = ntg * 16;
      int z = colb >> 8, coln = (colb & 255) + lcol;
      const float* bz = (z == 0) ? bq : (z == 1) ? bk : bv;
      _Float16* Hd = (z == 0) ? Q16 : (z == 1) ? K16 : V16;
      float bval = bz[coln];
#pragma unroll
      for (int mt = 0; mt < 2; ++mt) {
#pragma unroll
        for (int i = 0; i < 4; ++i) {
          int row = mt * 16 + quad * 4 + i;
          Hd[(size_t)rmapS[row] * 256 + coln] = f2h(acc[mt][j][i] + bval);
        }
      }
    }
  }
}

// ---------------- final projection: MFMA, B direct-from-global --------------
// 84 blocks x 512 thr; block owns 32 ktiles (1024 k). Et16 slice (32 KB)
// staged in LDS; B-fragments MFMA'd directly from global PWF (frag order ->
// lane*8 is a coalesced 16B/lane load; 32 independent loads/lane = deep MLP,
// no LDS staging for B). Atomics: 1536/block = 129K total (84-way/address,
// 4x less contention than the 336-block version -- the R9 43us bottleneck).
__global__ __launch_bounds__(512) void k_proj(
    const _Float16* __restrict__ Et16, const _Float16* __restrict__ PWF,
    float* __restrict__ out) {
  __shared__ _Float16 Ets[16 * 1032];   // stride 1032 (2-way banks), 33 KB
  int tid = threadIdx.x;
  int wave = tid >> 6, lane = tid & 63;
  int quad = lane >> 4, lcol = lane & 15;
  int kt0 = blockIdx.x * 32;            // global ktile base (2688/84 = 32)
  size_t kc0 = (size_t)kt0 * 32;        // k-column base

  // stage Et16: 16 rows x 1024 cols f16 = 2048 f16x8 groups
  for (int i = tid; i < 2048; i += 512) {
    int r = i >> 7, seg = i & 127;
    *(f16x8*)&Ets[r * 1032 + seg * 8] =
        *(const f16x8*)&Et16[(size_t)r * 86016 + kc0 + seg * 8];
  }
  __syncthreads();

  if (wave < 6) {
    f32x4 acc = {0.f, 0.f, 0.f, 0.f};
    const _Float16* bsrc = PWF + ((size_t)kt0 * 6 + wave) * 512 + lane * 8;
#pragma unroll 8
    for (int kt = 0; kt < 32; ++kt) {
      f16x8 af = *(const f16x8*)&Ets[lcol * 1032 + kt * 32 + quad * 8];
      f16x8 bf = *(const f16x8*)&bsrc[(size_t)kt * 6 * 512];
      acc = __builtin_amdgcn_mfma_f32_16x16x32_f16(af, bf, acc, 0, 0, 0);
    }
    int col = wave * 16 + lcol;
#pragma unroll
    for (int i = 0; i < 4; ++i) {
      int r = quad * 4 + i;
      atomicAdd(&out[(r >> 3) * 768 + col * 8 + (r & 7)], acc[i]);
    }
  }
}

// ---------------- launch ---------------------------------------------------
extern "C" void kernel_launch(void* const* d_in, const int* in_sizes, int n_in,
                              void* d_out, int out_size, void* d_ws,
                              size_t ws_size, hipStream_t stream) {
  const float* x     = (const float*)d_in[0];
  const float* emb_w = (const float*)d_in[1];
  const float* emb_b = (const float*)d_in[2];
  const float* Wq = (const float*)d_in[3];
  const float* bq = (const float*)d_in[4];
  const float* Wk = (const float*)d_in[5];
  const float* bk = (const float*)d_in[6];
  const float* Wv = (const float*)d_in[7];
  const float* bv = (const float*)d_in[8];
  const float* Wo = (const float*)d_in[9];
  const float* bo = (const float*)d_in[10];
  const float* g1 = (const float*)d_in[11];
  const float* b1 = (const float*)d_in[12];
  const float* gn = (const float*)d_in[13];
  const float* bn = (const float*)d_in[14];
  const float* PW = (const float*)d_in[15];
  const float* PB = (const float*)d_in[16];
  float* out = (float*)d_out;

  float* ws = (float*)d_ws;
  float* Etime   = ws;                              // NTD f32
  _Float16* Et16 = (_Float16*)(ws + (size_t)NTD);   // NTD f16
  _Float16* Q16  = (_Float16*)(ws + (size_t)NTD + NTD / 2);
  _Float16* K16  = Q16 + (size_t)NTD;
  _Float16* V16  = K16 + (size_t)NTD;
  _Float16* AO16 = V16 + (size_t)NTD;
  _Float16* WT2  = AO16 + (size_t)NTD;              // 4*65536 f16 (frag order)
  _Float16* PWF  = WT2 + 4 * 65536;                 // 8.25M f16 (proj frags)

  k_init<<<10432, 256, 0, stream>>>(Wq, Wk, Wv, Wo, x, emb_w, emb_b, PB, PW,
                                    WT2, Etime, Et16, PWF, out);
  for (int it = 0; it < 10; ++it) {
    k_attn_time<<<dim3(2, 8, 16), 512, 0, stream>>>(
        Et16, Q16, K16, V16, WT2, bq, bk, bv, AO16, (it == 0) ? 1 : 0);
    k_mega_var<<<168, 512, 0, stream>>>(
        AO16, WT2, bq, bk, bv, bo, g1, b1, gn, bn, Etime,
        Q16, K16, V16, Et16, (it < 9) ? 1 : 0);
  }
  k_proj<<<84, 512, 0, stream>>>(Et16, PWF, out);
}